// Round 15
// baseline (3843.506 us; speedup 1.0000x reference)
//
#include <hip/hip_runtime.h>
#include <cstddef>
#include <cstdint>

#define S_LEN 64
#define BATCH 128
#define T_LEN 32
#define E_DIM 256
#define VOCAB 32000
#define XDIM 1792
#define MPAD 4096

typedef unsigned short bfu;
typedef short short8 __attribute__((ext_vector_type(8)));
typedef float f32x4 __attribute__((ext_vector_type(4)));

__device__ __forceinline__ bfu f2b(float f) {
    unsigned int x = __float_as_uint(f);
    x += 0x7fffu + ((x >> 16) & 1u);
    return (bfu)(x >> 16);
}
__device__ __forceinline__ float b2f(bfu u) { return __uint_as_float(((unsigned)u) << 16); }
__device__ __forceinline__ f32x4 MFMA16(short8 a, short8 b, f32x4 c) {
    return __builtin_amdgcn_mfma_f32_16x16x32_bf16(a, b, c, 0, 0, 0);
}
__device__ __forceinline__ float sigm(float x) {
    return 1.f / (1.f + exp2f(x * -1.4426950408889634f));
}
__device__ __forceinline__ float ftanh(float x) {
    float xc = fminf(15.f, fmaxf(-15.f, x));
    float t = exp2f(xc * 2.8853900817779268f);
    return (t - 1.f) / (t + 1.f);
}

#define GLDS(gsrc, ldst)                                                       \
    __builtin_amdgcn_global_load_lds(                                          \
        (const __attribute__((address_space(1))) void*)(gsrc),                 \
        (__attribute__((address_space(3))) void*)(ldst), 16, 0, 0)

// ---------------------------------------------------------------- utilities
__global__ void zero_kernel(float* __restrict__ p, int n) {
    int i = blockIdx.x * 256 + threadIdx.x;
    if (i < n) p[i] = 0.f;
}

__global__ void conv_all(
    const float* __restrict__ s0, const float* __restrict__ s1,
    const float* __restrict__ s2, const float* __restrict__ s3,
    const float* __restrict__ s4, const float* __restrict__ s5,
    const float* __restrict__ s6, const float* __restrict__ s7,
    const float* __restrict__ s8,
    bfu* __restrict__ d0, bfu* __restrict__ d1, bfu* __restrict__ d2,
    bfu* __restrict__ d3, bfu* __restrict__ d4, bfu* __restrict__ d5,
    bfu* __restrict__ d6, bfu* __restrict__ d7, bfu* __restrict__ d8)
{
    int i = blockIdx.x * 256 + threadIdx.x;
    if (i >= 15941632) return;
    const float* s; bfu* d; int base;
    if      (i <   98304) { s = s0; d = d0; base = 0; }
    else if (i <  196608) { s = s1; d = d1; base = 98304; }
    else if (i <  393216) { s = s2; d = d2; base = 196608; }
    else if (i <  589824) { s = s3; d = d3; base = 393216; }
    else if (i <  720896) { s = s4; d = d4; base = 589824; }
    else if (i <  917504) { s = s5; d = d5; base = 720896; }
    else if (i < 1409024) { s = s6; d = d6; base = 917504; }
    else if (i < 1605632) { s = s7; d = d7; base = 1409024; }
    else                  { s = s8; d = d8; base = 1605632; }
    int j = i - base;
    float4 v = ((const float4*)s)[j];
    ushort4 o;
    o.x = f2b(v.x); o.y = f2b(v.y); o.z = f2b(v.z); o.w = f2b(v.w);
    ((ushort4*)d)[j] = o;
}

// WahT[k][j] = bf16(W_attn[j][k])
__global__ void transpose_wah(const float* __restrict__ W_attn, bfu* __restrict__ WahT) {
    int i = blockIdx.x * 256 + threadIdx.x;
    if (i >= 262144) return;
    int k = i >> 9, j = i & 511;
    WahT[i] = f2b(W_attn[(size_t)j * 1536 + k]);
}

__global__ void gather_emb(const float* __restrict__ table, const int* __restrict__ idx,
                           bfu* __restrict__ out, int total) {
    int i = blockIdx.x * 256 + threadIdx.x;
    if (i >= total) return;
    int row = i >> 8, k = i & 255;
    out[i] = f2b(table[(size_t)idx[row] * E_DIM + k]);
}

__global__ void gather_trg(const float* __restrict__ table, const int* __restrict__ trg,
                           bfu* __restrict__ Xb, int total) {
    int i = blockIdx.x * 256 + threadIdx.x;
    if (i >= total) return;
    int row = i >> 8, k = i & 255;
    Xb[(size_t)row * XDIM + 1536 + k] = f2b(table[(size_t)trg[row] * E_DIM + k]);
}

// ----------------------------------------------- generic bf16 MFMA GEMM (NT)
__global__ __launch_bounds__(256) void gemm_bf16(
    const bfu* __restrict__ A0, int lda0, const bfu* __restrict__ W0, int ldw0,
    float* __restrict__ C0, int ldc0, const float* __restrict__ bias0, int K0,
    const bfu* __restrict__ A1, int lda1, const bfu* __restrict__ W1, int ldw1,
    float* __restrict__ C1, int ldc1, const float* __restrict__ bias1, int K1,
    int act, bfu* __restrict__ Cb0)
{
    const int z = blockIdx.z;
    const bfu* A = z ? A1 : A0;
    const bfu* W = z ? W1 : W0;
    float*     C = z ? C1 : C0;
    const float* bias = z ? bias1 : bias0;
    bfu*       Cb = z ? nullptr : Cb0;
    const int lda = z ? lda1 : lda0;
    const int ldw = z ? ldw1 : ldw0;
    const int ldc = z ? ldc1 : ldc0;
    const int K   = z ? K1 : K0;

    __shared__ short lds[2][2][4096];
    const int tid  = threadIdx.x;
    const int wid  = tid >> 6, lane = tid & 63;
    const int l15  = lane & 15, lk = lane >> 4;
    const int wr   = (wid >> 1) * 64, wc = (wid & 1) * 64;
    const size_t row0 = (size_t)blockIdx.y * 128;
    const size_t col0 = (size_t)blockIdx.x * 128;

    const int r0 = tid & 127, kc0 = tid >> 7;
    const int kc1 = kc0 + 2;
    const int sb0 = (wid * 64) * 16;
    const int sb1 = (wid * 64 + 256) * 16;

    f32x4 acc[4][4];
#pragma unroll
    for (int m = 0; m < 4; ++m)
#pragma unroll
        for (int n = 0; n < 4; ++n) acc[m][n] = (f32x4){0.f, 0.f, 0.f, 0.f};

    auto stage = [&](int buf, int kt) {
        char* ba = (char*)&lds[buf][0][0];
        char* bb = (char*)&lds[buf][1][0];
        GLDS(A + (row0 + r0) * (size_t)lda + kt + kc0 * 8, ba + sb0);
        GLDS(A + (row0 + r0) * (size_t)lda + kt + kc1 * 8, ba + sb1);
        GLDS(W + (col0 + r0) * (size_t)ldw + kt + kc0 * 8, bb + sb0);
        GLDS(W + (col0 + r0) * (size_t)ldw + kt + kc1 * 8, bb + sb1);
    };

    stage(0, 0);
    __syncthreads();
    const int nk = K >> 5;
    for (int t = 0; t < nk; ++t) {
        const int buf = t & 1;
        if (t + 1 < nk) stage(buf ^ 1, (t + 1) << 5);
        short8 af[4], bf_[4];
#pragma unroll
        for (int m = 0; m < 4; ++m)
            af[m] = *(const short8*)&lds[buf][0][lk * 1024 + (wr + m * 16 + l15) * 8];
#pragma unroll
        for (int n = 0; n < 4; ++n)
            bf_[n] = *(const short8*)&lds[buf][1][lk * 1024 + (wc + n * 16 + l15) * 8];
#pragma unroll
        for (int m = 0; m < 4; ++m)
#pragma unroll
            for (int n = 0; n < 4; ++n)
                acc[m][n] = MFMA16(af[m], bf_[n], acc[m][n]);
        __syncthreads();
    }

    float bv[4];
#pragma unroll
    for (int n = 0; n < 4; ++n)
        bv[n] = bias ? bias[col0 + wc + n * 16 + l15] : 0.f;
    const size_t crow = row0 + wr + lk * 4;
#pragma unroll
    for (int m = 0; m < 4; ++m) {
#pragma unroll
        for (int q = 0; q < 4; ++q) {
            const size_t r = crow + m * 16 + q;
            float* cp = C + r * ldc + col0 + wc + l15;
            bfu*   cb = Cb ? (Cb + r * ldc + col0 + wc + l15) : nullptr;
#pragma unroll
            for (int n = 0; n < 4; ++n) {
                float v = acc[m][n][q] + bv[n];
                if (act) v = ftanh(v);
                cp[n * 16] = v;
                if (Cb) cb[n * 16] = f2b(v);
            }
        }
    }
}

// ----------------------------------------------- big output GEMM, 128x256 tile
// BM=128 (M=3968=31x128 exact), BN=256, BK=32; LDS 48KB -> 3 blocks/CU.
// grid 3875 = 125 bx * 31 by, by fast (row-consumers of a W column concurrent).
__global__ __launch_bounds__(512) void gemm_big(
    const bfu* __restrict__ A, const bfu* __restrict__ W,
    float* __restrict__ C, const float* __restrict__ bias,
    bfu* __restrict__ Lb, int obf)
{
    __shared__ short ldsA[2][4096];   // [kc4][128][8]  8KB each
    __shared__ short ldsW[2][8192];   // [kc4][256][8] 16KB each
    const int tid = threadIdx.x;
    const int wid = tid >> 6, lane = tid & 63;
    const int l15 = lane & 15, lk = lane >> 4;
    const int wr = (wid >> 2) * 64;       // 2 M-waves
    const int wcc = (wid & 3) * 64;       // 4 N-waves
    const int fid = blockIdx.x;           // 0..3874
    const int bx = fid / 31, by = fid % 31;
    const size_t row0 = (size_t)by * 128;
    const size_t col0 = (size_t)bx * 256;

    f32x4 acc[4][4];
#pragma unroll
    for (int m = 0; m < 4; ++m)
#pragma unroll
        for (int n = 0; n < 4; ++n) acc[m][n] = (f32x4){0.f, 0.f, 0.f, 0.f};

    const int a_kc = tid >> 7, a_row = tid & 127;          // 512 chunks
    auto stage = [&](int buf, int kt) {
        char* ba = (char*)&ldsA[buf][0];
        char* bb = (char*)&ldsW[buf][0];
        GLDS(A + (row0 + a_row) * (size_t)XDIM + kt + a_kc * 8, ba + (wid * 64) * 16);
#pragma unroll
        for (int it = 0; it < 2; ++it) {
            int c = it * 512 + tid;
            int kc = c >> 8, row = c & 255;
            GLDS(W + (col0 + row) * (size_t)XDIM + kt + kc * 8,
                 bb + (it * 512 + wid * 64) * 16);
        }
    };

    stage(0, 0);
    __syncthreads();
    for (int t = 0; t < 56; ++t) {
        const int buf = t & 1;
        if (t < 55) stage(buf ^ 1, (t + 1) * 32);
        short8 af[4], bf_[4];
#pragma unroll
        for (int m = 0; m < 4; ++m)
            af[m] = *(const short8*)&ldsA[buf][(lk * 128 + wr + m * 16 + l15) * 8];
#pragma unroll
        for (int n = 0; n < 4; ++n)
            bf_[n] = *(const short8*)&ldsW[buf][(lk * 256 + wcc + n * 16 + l15) * 8];
#pragma unroll
        for (int m = 0; m < 4; ++m)
#pragma unroll
            for (int n = 0; n < 4; ++n)
                acc[m][n] = MFMA16(af[m], bf_[n], acc[m][n]);
        __syncthreads();
    }
    {
        float bv[4];
#pragma unroll
        for (int n = 0; n < 4; ++n) bv[n] = bias[col0 + wcc + n * 16 + l15];
#pragma unroll
        for (int m = 0; m < 4; ++m) {
#pragma unroll
            for (int q = 0; q < 4; ++q) {
                const size_t r = row0 + wr + lk * 4 + m * 16 + q;
                if (obf) {
                    bfu* cp = Lb + r * VOCAB + col0 + wcc + l15;
#pragma unroll
                    for (int n = 0; n < 4; ++n) {
                        unsigned hb = f2b(acc[m][n][q] + bv[n]);
                        unsigned ot = (unsigned)__shfl_xor((int)hb, 1);
                        if ((lane & 1) == 0)
                            *(unsigned*)(cp + n * 16) = (hb & 0xffffu) | (ot << 16);
                    }
                } else {
                    float* cp = C + r * VOCAB + col0 + wcc + l15;
#pragma unroll
                    for (int n = 0; n < 4; ++n) cp[n * 16] = acc[m][n][q] + bv[n];
                }
            }
        }
    }
}

// ----------------------------------------------- fused encoder step (batch-split)
__global__ __launch_bounds__(256) void enc_step(
    const float* __restrict__ gi_f, const float* __restrict__ gi_b,
    const bfu* __restrict__ Whhf_b, const bfu* __restrict__ Whhb_b,
    const float* __restrict__ bhh_f, const float* __restrict__ bhh_b,
    const float* __restrict__ hin, float* __restrict__ hout,
    const bfu* __restrict__ hbin, bfu* __restrict__ hbout,
    bfu* __restrict__ encbt, int s)
{
    __shared__ short Bs[64 * 48 * 8];
    const int tid = threadIdx.x;
    const int wid = tid >> 6, lane = tid & 63;
    const int l15 = lane & 15, lk = lane >> 4;
    const int dir = blockIdx.z;
    const int u0 = blockIdx.x * 16;
    const int bb0 = blockIdx.y * 64;
    const int p = dir ? (S_LEN - 1 - s) : s;
    const bfu* Whh = dir ? Whhb_b : Whhf_b;
    const float* bhh = dir ? bhh_b : bhh_f;
    const float* gi = (dir ? gi_b : gi_f) + (size_t)p * BATCH * 1536;

    {
        char* bb = (char*)Bs;
#pragma unroll
        for (int it = 0; it < 12; ++it) {
            int c = it * 256 + tid;
            int r48 = c % 48, kc = c / 48;
            int wr = (r48 >> 4) * 512 + u0 + (r48 & 15);
            GLDS(Whh + (size_t)wr * 512 + kc * 8, bb + (it * 256 + wid * 64) * 16);
        }
    }
    __syncthreads();

    const bfu* ap0 = hbin + (size_t)(bb0 + wid * 16 + l15) * 1024 + dir * 512 + lk * 8;
    f32x4 acc[3];
#pragma unroll
    for (int g = 0; g < 3; ++g) acc[g] = (f32x4){0.f, 0.f, 0.f, 0.f};

#pragma unroll
    for (int kk = 0; kk < 16; ++kk) {
        short8 a0 = *(const short8*)(ap0 + kk * 32);
#pragma unroll
        for (int g = 0; g < 3; ++g) {
            short8 bf_ = *(const short8*)&Bs[((kk * 4 + lk) * 48 + g * 16 + l15) * 8];
            acc[g] = MFMA16(a0, bf_, acc[g]);
        }
    }

    const int u = u0 + l15;
    const float bR = bhh[u], bZ = bhh[512 + u], bN = bhh[1024 + u];
#pragma unroll
    for (int q = 0; q < 4; ++q) {
        const int b = bb0 + wid * 16 + lk * 4 + q;
        const float* gib = gi + (size_t)b * 1536;
        float rr = sigm(gib[u] + acc[0][q] + bR);
        float zz = sigm(gib[512 + u] + acc[1][q] + bZ);
        float nn = ftanh(gib[1024 + u] + rr * (acc[2][q] + bN));
        float h2 = (1.f - zz) * nn + zz * hin[(size_t)b * 1024 + dir * 512 + u];
        hout[(size_t)b * 1024 + dir * 512 + u] = h2;
        hbout[(size_t)b * 1024 + dir * 512 + u] = f2b(h2);
        encbt[((size_t)b * S_LEN + p) * 1024 + dir * 512 + u] = f2b(h2);
    }
}

// ----------------------------------------------- fused hp + attention step
__global__ __launch_bounds__(256) void attn_fused(
    const bfu* __restrict__ hb, const bfu* __restrict__ WahT,
    const bfu* __restrict__ encp_b, const bfu* __restrict__ encbt,
    const float* __restrict__ v_attn, const int* __restrict__ src,
    bfu* __restrict__ wbuf, bfu* __restrict__ Xb, int t)
{
    __shared__ float hls[512];
    __shared__ float vas[512];
    __shared__ float hps[512];
    __shared__ float sc[64];
    const int b = blockIdx.x, tid = threadIdx.x;
    for (int i = tid; i < 512; i += 256) {
        hls[i] = b2f(hb[(size_t)b * 512 + i]);
        vas[i] = v_attn[i];
    }
    __syncthreads();
    {
        const unsigned* wt = (const unsigned*)WahT;
        float a0 = 0.f, a1 = 0.f;
#pragma unroll 8
        for (int k = 0; k < 512; ++k) {
            unsigned w = wt[k * 256 + tid];
            float hk = hls[k];
            a0 += hk * __uint_as_float(w << 16);
            a1 += hk * __uint_as_float(w & 0xffff0000u);
        }
        hps[tid * 2]     = a0;
        hps[tid * 2 + 1] = a1;
    }
    __syncthreads();
    const int s = tid >> 2, l4 = tid & 3;
    const unsigned* epb = (const unsigned*)(encp_b + ((size_t)b * S_LEN + s) * 512);
    float part = 0.f;
#pragma unroll 4
    for (int dp = l4; dp < 256; dp += 4) {
        unsigned w = epb[dp];
        part += vas[2 * dp]     * ftanh(__uint_as_float(w << 16) + hps[2 * dp]);
        part += vas[2 * dp + 1] * ftanh(__uint_as_float(w & 0xffff0000u) + hps[2 * dp + 1]);
    }
    part += __shfl_xor(part, 1);
    part += __shfl_xor(part, 2);
    if (l4 == 0) sc[s] = (src[s * BATCH + b] != 0) ? part : -1e10f;
    __syncthreads();
    if (tid < 64) {
        float x = sc[tid], mx = x;
        for (int o = 1; o < 64; o <<= 1) mx = fmaxf(mx, __shfl_xor(mx, o));
        float e = expf(x - mx), s2 = e;
        for (int o = 1; o < 64; o <<= 1) s2 += __shfl_xor(s2, o);
        sc[tid] = e / s2;
    }
    __syncthreads();
    bfu* xw = Xb + ((size_t)t * BATCH + b) * XDIM + 512;
#pragma unroll
    for (int c = 0; c < 4; ++c) {
        int e = tid + 256 * c;
        float a2 = 0.f;
#pragma unroll 8
        for (int s2 = 0; s2 < S_LEN; ++s2) a2 += sc[s2] * b2f(encbt[((size_t)b * S_LEN + s2) * 1024 + e]);
        bfu v = f2b(a2);
        wbuf[(size_t)b * 1024 + e] = v;
        xw[e] = v;
    }
}

// ----------------------------------------------- fused decoder GEMM + gate (batch-split)
__global__ __launch_bounds__(256) void dec_step(
    const float* __restrict__ gie, const bfu* __restrict__ Whhd_b,
    const bfu* __restrict__ Wihd_b, const float* __restrict__ bhh_d,
    const bfu* __restrict__ hbin, const bfu* __restrict__ wbuf,
    const float* __restrict__ hin, float* __restrict__ hout,
    bfu* __restrict__ hbout, bfu* __restrict__ Xb, int t)
{
    __shared__ short Bh[64 * 48 * 8];
    __shared__ short Bw[128 * 48 * 8];
    const int tid = threadIdx.x;
    const int wid = tid >> 6, lane = tid & 63;
    const int l15 = lane & 15, lk = lane >> 4;
    const int u0 = blockIdx.x * 16;
    const int bb0 = blockIdx.y * 64;

    {
        char* bb = (char*)Bh;
#pragma unroll
        for (int it = 0; it < 12; ++it) {
            int c = it * 256 + tid;
            int r48 = c % 48, kc = c / 48;
            int wr = (r48 >> 4) * 512 + u0 + (r48 & 15);
            GLDS(Whhd_b + (size_t)wr * 512 + kc * 8, bb + (it * 256 + wid * 64) * 16);
        }
        char* bw = (char*)Bw;
#pragma unroll
        for (int it = 0; it < 24; ++it) {
            int c = it * 256 + tid;
            int r48 = c % 48, kc = c / 48;
            int wr = (r48 >> 4) * 512 + u0 + (r48 & 15);
            GLDS(Wihd_b + (size_t)wr * 1280 + 256 + kc * 8, bw + (it * 256 + wid * 64) * 16);
        }
    }
    __syncthreads();

    f32x4 accR, accZ, accNH, accNW;
    accR = (f32x4){0.f, 0.f, 0.f, 0.f};
    accZ = (f32x4){0.f, 0.f, 0.f, 0.f};
    accNH = (f32x4){0.f, 0.f, 0.f, 0.f};
    accNW = (f32x4){0.f, 0.f, 0.f, 0.f};

    {
        const bfu* ap0 = hbin + (size_t)(bb0 + wid * 16 + l15) * 512 + lk * 8;
#pragma unroll
        for (int kk = 0; kk < 16; ++kk) {
            short8 a0 = *(const short8*)(ap0 + kk * 32);
            short8 br = *(const short8*)&Bh[((kk * 4 + lk) * 48 + l15) * 8];
            short8 bz = *(const short8*)&Bh[((kk * 4 + lk) * 48 + 16 + l15) * 8];
            short8 bn = *(const short8*)&Bh[((kk * 4 + lk) * 48 + 32 + l15) * 8];
            accR = MFMA16(a0, br, accR);
            accZ = MFMA16(a0, bz, accZ);
            accNH = MFMA16(a0, bn, accNH);
        }
    }
    {
        const bfu* ap0 = wbuf + (size_t)(bb0 + wid * 16 + l15) * 1024 + lk * 8;
#pragma unroll
        for (int kk = 0; kk < 32; ++kk) {
            short8 a0 = *(const short8*)(ap0 + kk * 32);
            short8 br = *(const short8*)&Bw[((kk * 4 + lk) * 48 + l15) * 8];
            short8 bz = *(const short8*)&Bw[((kk * 4 + lk) * 48 + 16 + l15) * 8];
            short8 bn = *(const short8*)&Bw[((kk * 4 + lk) * 48 + 32 + l15) * 8];
            accR = MFMA16(a0, br, accR);
            accZ = MFMA16(a0, bz, accZ);
            accNW = MFMA16(a0, bn, accNW);
        }
    }

    const int u = u0 + l15;
    const float bR = bhh_d[u], bZ = bhh_d[512 + u], bN = bhh_d[1024 + u];
#pragma unroll
    for (int q = 0; q < 4; ++q) {
        const int b = bb0 + wid * 16 + lk * 4 + q;
        const float* geb = gie + ((size_t)t * BATCH + b) * 1536;
        float rr = sigm(geb[u] + accR[q] + bR);
        float zz = sigm(geb[512 + u] + accZ[q] + bZ);
        float nn = ftanh(geb[1024 + u] + accNW[q] + rr * (accNH[q] + bN));
        float h2 = (1.f - zz) * nn + zz * hin[(size_t)b * 512 + u];
        hout[(size_t)b * 512 + u] = h2;
        hbout[(size_t)b * 512 + u] = f2b(h2);
        Xb[((size_t)t * BATCH + b) * XDIM + u] = f2b(h2);
    }
}

// --------------------------- log-softmax (dual: bf16 logits or f32 in-place)
__global__ __launch_bounds__(256) void log_softmax_fill(
    const bfu* __restrict__ Lb, float* __restrict__ out, int obf)
{
    __shared__ float sm[256], ss[256];
    const int row = blockIdx.x;
    const int tid = threadIdx.x;
    float* po = out + (size_t)row * VOCAB;
    if (row >= 3968) {
        float4* p4 = (float4*)po;
        for (int i = tid; i < 8000; i += 256) {
            float4 v = {0.f, 0.f, 0.f, 0.f};
            if (i == 0) v.z = 100.f;     // EOS=2
            p4[i] = v;
        }
        return;
    }
    float m = -3.4e38f, ssum = 0.f;
    if (obf) {
        const uint4* pb = (const uint4*)(Lb + (size_t)row * VOCAB);
        for (int i = tid; i < 4000; i += 256) {
            uint4 w = pb[i];
            float x[8];
            x[0] = __uint_as_float(w.x << 16); x[1] = __uint_as_float(w.x & 0xffff0000u);
            x[2] = __uint_as_float(w.y << 16); x[3] = __uint_as_float(w.y & 0xffff0000u);
            x[4] = __uint_as_float(w.z << 16); x[5] = __uint_as_float(w.z & 0xffff0000u);
            x[6] = __uint_as_float(w.w << 16); x[7] = __uint_as_float(w.w & 0xffff0000u);
            float mx = x[0];
#pragma unroll
            for (int j = 1; j < 8; ++j) mx = fmaxf(mx, x[j]);
            float mn = fmaxf(m, mx);
            float e = 0.f;
#pragma unroll
            for (int j = 0; j < 8; ++j) e += expf(x[j] - mn);
            ssum = ssum * expf(m - mn) + e;
            m = mn;
        }
    } else {
        const float4* p4 = (const float4*)po;
        for (int i = tid; i < 8000; i += 256) {
            float4 v = p4[i];
            float mx = fmaxf(fmaxf(v.x, v.y), fmaxf(v.z, v.w));
            float mn = fmaxf(m, mx);
            ssum = ssum * expf(m - mn) + expf(v.x - mn) + expf(v.y - mn)
                 + expf(v.z - mn) + expf(v.w - mn);
            m = mn;
        }
    }
    sm[tid] = m; ss[tid] = ssum;
    __syncthreads();
    for (int off = 128; off > 0; off >>= 1) {
        if (tid < off) {
            float m2 = sm[tid + off], s2 = ss[tid + off];
            float M = fmaxf(sm[tid], m2);
            ss[tid] = ss[tid] * expf(sm[tid] - M) + s2 * expf(m2 - M);
            sm[tid] = M;
        }
        __syncthreads();
    }
    const float lse = sm[0] + logf(ss[0]);
    if (obf) {
        const uint4* pb = (const uint4*)(Lb + (size_t)row * VOCAB);
        float4* p4 = (float4*)po;
        for (int i = tid; i < 4000; i += 256) {
            uint4 w = pb[i];
            float4 a, b4;
            a.x = __uint_as_float(w.x << 16) - lse;
            a.y = __uint_as_float(w.x & 0xffff0000u) - lse;
            a.z = __uint_as_float(w.y << 16) - lse;
            a.w = __uint_as_float(w.y & 0xffff0000u) - lse;
            b4.x = __uint_as_float(w.z << 16) - lse;
            b4.y = __uint_as_float(w.z & 0xffff0000u) - lse;
            b4.z = __uint_as_float(w.w << 16) - lse;
            b4.w = __uint_as_float(w.w & 0xffff0000u) - lse;
            p4[i * 2] = a;
            p4[i * 2 + 1] = b4;
        }
    } else {
        float4* p4 = (float4*)po;
        for (int i = tid; i < 8000; i += 256) {
            float4 v = p4[i];
            v.x -= lse; v.y -= lse; v.z -= lse; v.w -= lse;
            p4[i] = v;
        }
    }
}

// ==================================================================== launch
extern "C" void kernel_launch(void* const* d_in, const int* in_sizes, int n_in,
                              void* d_out, int out_size, void* d_ws, size_t ws_size,
                              hipStream_t stream)
{
    const int*   src     = (const int*)d_in[0];
    const int*   trg     = (const int*)d_in[2];
    const float* emb_enc = (const float*)d_in[3];
    const float* emb_dec = (const float*)d_in[4];
    const float* Wih_f   = (const float*)d_in[5];
    const float* Whh_f   = (const float*)d_in[6];
    const float* bih_f   = (const float*)d_in[7];
    const float* bhh_f   = (const float*)d_in[8];
    const float* Wih_b   = (const float*)d_in[9];
    const float* Whh_b   = (const float*)d_in[10];
    const float* bih_b   = (const float*)d_in[11];
    const float* bhh_b   = (const float*)d_in[12];
    const float* W_fc    = (const float*)d_in[13];
    const float* b_fc    = (const float*)d_in[14];
    const float* W_attn  = (const float*)d_in[15];
    const float* b_attn  = (const float*)d_in[16];
    const float* v_attn  = (const float*)d_in[17];
    const float* Wih_d   = (const float*)d_in[18];
    const float* Whh_d   = (const float*)d_in[19];
    const float* bih_d   = (const float*)d_in[20];
    const float* bhh_d   = (const float*)d_in[21];
    const float* W_out   = (const float*)d_in[22];
    const float* b_out   = (const float*)d_in[23];
    float* out = (float*)d_out;

    char* wsb = (char*)d_ws;
    size_t off = 0;
    auto alloc = [&](size_t bytes) { void* q = wsb + off; off = (off + bytes + 255) & ~(size_t)255; return q; };
    bfu*   emb_b   = (bfu*)alloc((size_t)8192 * 256 * 2);
    bfu*   encbt_b = (bfu*)alloc((size_t)8192 * 1024 * 2);
    float* encp    = (float*)alloc((size_t)8192 * 512 * 4);
    bfu*   encp_b  = (bfu*)alloc((size_t)8192 * 512 * 2);
    float* gi_f    = (float*)alloc((size_t)8192 * 1536 * 4);
    float* gi_b    = (float*)alloc((size_t)8192 * 1536 * 4);
    float* gie     = (float*)alloc((size_t)3968 * 1536 * 4);
    bfu*   wbuf    = (bfu*)alloc((size_t)128 * 1024 * 2);
    float* hA      = (float*)alloc((size_t)128 * 1024 * 4);
    float* hB      = (float*)alloc((size_t)128 * 1024 * 4);
    bfu*   hbA     = (bfu*)alloc((size_t)128 * 1024 * 2);
    bfu*   hbB     = (bfu*)alloc((size_t)128 * 1024 * 2);
    float* hdA     = (float*)alloc((size_t)128 * 512 * 4);
    float* hdB     = (float*)alloc((size_t)128 * 512 * 4);
    bfu*   hdbA    = (bfu*)alloc((size_t)128 * 512 * 2);
    bfu*   hdbB    = (bfu*)alloc((size_t)128 * 512 * 2);
    bfu*   Xb      = (bfu*)alloc((size_t)MPAD * XDIM * 2);
    bfu*   Wihf_b  = (bfu*)alloc((size_t)1536 * 256 * 2);
    bfu*   Wihb_b  = (bfu*)alloc((size_t)1536 * 256 * 2);
    bfu*   Whhf_b  = (bfu*)alloc((size_t)1536 * 512 * 2);
    bfu*   Whhb_b  = (bfu*)alloc((size_t)1536 * 512 * 2);
    bfu*   Wfc_b   = (bfu*)alloc((size_t)512 * 1024 * 2);
    bfu*   Wattn_b = (bfu*)alloc((size_t)512 * 1536 * 2);
    bfu*   WahT    = (bfu*)alloc((size_t)512 * 512 * 2);
    bfu*   Wihd_b  = (bfu*)alloc((size_t)1536 * 1280 * 2);
    bfu*   Whhd_b  = (bfu*)alloc((size_t)1536 * 512 * 2);
    bfu*   Wout_b  = (bfu*)alloc((size_t)VOCAB * XDIM * 2);

    const size_t lb_bytes = (size_t)MPAD * VOCAB * 2;
    bfu* Lb = nullptr;
    if (ws_size >= off + lb_bytes + 256) Lb = (bfu*)alloc(lb_bytes);
    const int obf = (Lb != nullptr) ? 1 : 0;

    conv_all<<<(15941632 + 255) / 256, 256, 0, stream>>>(
        Wih_f, Wih_b, Whh_f, Whh_b, W_fc, W_attn, Wih_d, Whh_d, W_out,
        Wihf_b, Wihb_b, Whhf_b, Whhb_b, Wfc_b, Wattn_b, Wihd_b, Whhd_b, Wout_b);
    transpose_wah<<<1024, 256, 0, stream>>>(W_attn, WahT);

    gather_emb<<<(8192 * 256 + 255) / 256, 256, 0, stream>>>(emb_enc, src, emb_b, 8192 * 256);
    gather_trg<<<(3968 * 256 + 255) / 256, 256, 0, stream>>>(emb_dec, trg, Xb, 3968 * 256);
    zero_kernel<<<(131072 + 255) / 256, 256, 0, stream>>>(hA, 131072);
    zero_kernel<<<(65536 + 255) / 256, 256, 0, stream>>>((float*)hbA, 65536);

    // gi for all encoder steps, both dirs
    gemm_bf16<<<dim3(12, 64, 2), 256, 0, stream>>>(
        emb_b, 256, Wihf_b, 256, gi_f, 1536, bih_f, 256,
        emb_b, 256, Wihb_b, 256, gi_b, 1536, bih_b, 256, 0, nullptr);
    // gi_e for all decoder steps
    gemm_bf16<<<dim3(12, 31, 1), 256, 0, stream>>>(
        Xb + 1536, XDIM, Wihd_b, 1280, gie, 1536, bih_d, 256,
        Xb + 1536, XDIM, Wihd_b, 1280, gie, 1536, bih_d, 256, 0, nullptr);

    // encoder: 64 fused steps (batch-split grid)
    for (int s = 0; s < S_LEN; ++s) {
        const float* hin  = (s & 1) ? hB : hA;
        float*       hout = (s & 1) ? hA : hB;
        const bfu*   hbin = (s & 1) ? hbB : hbA;
        bfu*         hbout = (s & 1) ? hbA : hbB;
        enc_step<<<dim3(32, 2, 2), 256, 0, stream>>>(
            gi_f, gi_b, Whhf_b, Whhb_b, bhh_f, bhh_b,
            hin, hout, hbin, hbout, encbt_b, s);
    }
    // hid = tanh([hf,hb] @ W_fc^T + b_fc)
    gemm_bf16<<<dim3(4, 1, 1), 256, 0, stream>>>(
        hbA, 1024, Wfc_b, 1024, hdA, 512, b_fc, 1024,
        hbA, 1024, Wfc_b, 1024, hdA, 512, b_fc, 1024, 1, hdbA);
    // enc_proj (f32 + bf16 mirror)
    gemm_bf16<<<dim3(4, 64, 1), 256, 0, stream>>>(
        encbt_b, 1024, Wattn_b + 512, 1536, encp, 512, b_attn, 1024,
        encbt_b, 1024, Wattn_b + 512, 1536, encp, 512, b_attn, 1024, 0, encp_b);

    // decoder: 31 steps x 2 launches
    for (int t = 0; t < T_LEN - 1; ++t) {
        const float* hin  = (t & 1) ? hdB : hdA;
        float*       hout = (t & 1) ? hdA : hdB;
        const bfu*   hbin = (t & 1) ? hdbB : hdbA;
        bfu*         hbout = (t & 1) ? hdbA : hdbB;
        attn_fused<<<BATCH, 256, 0, stream>>>(hbin, WahT, encp_b, encbt_b,
                                              v_attn, src, wbuf, Xb, t);
        dec_step<<<dim3(32, 2), 256, 0, stream>>>(
            gie, Whhd_b, Wihd_b, bhh_d, hbin, wbuf, hin, hout, hbout, Xb, t);
    }

    // logits (bf16 if room) + log-softmax + fill plane
    gemm_big<<<dim3(3875, 1), 512, 0, stream>>>(Xb, Wout_b, out, b_out, Lb, obf);
    log_softmax_fill<<<4096, 256, 0, stream>>>(Lb, out, obf);
}

// Round 16
// 3710.137 us; speedup vs baseline: 1.0359x; 1.0359x over previous
//
#include <hip/hip_runtime.h>
#include <cstddef>
#include <cstdint>

#define S_LEN 64
#define BATCH 128
#define T_LEN 32
#define E_DIM 256
#define VOCAB 32000
#define XDIM 1792
#define MPAD 4096

typedef unsigned short bfu;
typedef short short8 __attribute__((ext_vector_type(8)));
typedef float f32x4 __attribute__((ext_vector_type(4)));

__device__ __forceinline__ bfu f2b(float f) {
    unsigned int x = __float_as_uint(f);
    x += 0x7fffu + ((x >> 16) & 1u);
    return (bfu)(x >> 16);
}
__device__ __forceinline__ float b2f(bfu u) { return __uint_as_float(((unsigned)u) << 16); }
__device__ __forceinline__ f32x4 MFMA16(short8 a, short8 b, f32x4 c) {
    return __builtin_amdgcn_mfma_f32_16x16x32_bf16(a, b, c, 0, 0, 0);
}
__device__ __forceinline__ float sigm(float x) {
    return 1.f / (1.f + exp2f(x * -1.4426950408889634f));
}
__device__ __forceinline__ float ftanh(float x) {
    float xc = fminf(15.f, fmaxf(-15.f, x));
    float t = exp2f(xc * 2.8853900817779268f);
    return (t - 1.f) / (t + 1.f);
}

#define GLDS(gsrc, ldst)                                                       \
    __builtin_amdgcn_global_load_lds(                                          \
        (const __attribute__((address_space(1))) void*)(gsrc),                 \
        (__attribute__((address_space(3))) void*)(ldst), 16, 0, 0)

// ---------------------------------------------------------------- utilities
__global__ void zero_kernel(float* __restrict__ p, int n) {
    int i = blockIdx.x * 256 + threadIdx.x;
    if (i < n) p[i] = 0.f;
}

__global__ void conv_all(
    const float* __restrict__ s0, const float* __restrict__ s1,
    const float* __restrict__ s2, const float* __restrict__ s3,
    const float* __restrict__ s4, const float* __restrict__ s5,
    const float* __restrict__ s6, const float* __restrict__ s7,
    const float* __restrict__ s8,
    bfu* __restrict__ d0, bfu* __restrict__ d1, bfu* __restrict__ d2,
    bfu* __restrict__ d3, bfu* __restrict__ d4, bfu* __restrict__ d5,
    bfu* __restrict__ d6, bfu* __restrict__ d7, bfu* __restrict__ d8)
{
    int i = blockIdx.x * 256 + threadIdx.x;
    if (i >= 15941632) return;
    const float* s; bfu* d; int base;
    if      (i <   98304) { s = s0; d = d0; base = 0; }
    else if (i <  196608) { s = s1; d = d1; base = 98304; }
    else if (i <  393216) { s = s2; d = d2; base = 196608; }
    else if (i <  589824) { s = s3; d = d3; base = 393216; }
    else if (i <  720896) { s = s4; d = d4; base = 589824; }
    else if (i <  917504) { s = s5; d = d5; base = 720896; }
    else if (i < 1409024) { s = s6; d = d6; base = 917504; }
    else if (i < 1605632) { s = s7; d = d7; base = 1409024; }
    else                  { s = s8; d = d8; base = 1605632; }
    int j = i - base;
    float4 v = ((const float4*)s)[j];
    ushort4 o;
    o.x = f2b(v.x); o.y = f2b(v.y); o.z = f2b(v.z); o.w = f2b(v.w);
    ((ushort4*)d)[j] = o;
}

// WahT[k][j] = bf16(W_attn[j][k])
__global__ void transpose_wah(const float* __restrict__ W_attn, bfu* __restrict__ WahT) {
    int i = blockIdx.x * 256 + threadIdx.x;
    if (i >= 262144) return;
    int k = i >> 9, j = i & 511;
    WahT[i] = f2b(W_attn[(size_t)j * 1536 + k]);
}

__global__ void gather_emb(const float* __restrict__ table, const int* __restrict__ idx,
                           bfu* __restrict__ out, int total) {
    int i = blockIdx.x * 256 + threadIdx.x;
    if (i >= total) return;
    int row = i >> 8, k = i & 255;
    out[i] = f2b(table[(size_t)idx[row] * E_DIM + k]);
}

__global__ void gather_trg(const float* __restrict__ table, const int* __restrict__ trg,
                           bfu* __restrict__ Xb, int total) {
    int i = blockIdx.x * 256 + threadIdx.x;
    if (i >= total) return;
    int row = i >> 8, k = i & 255;
    Xb[(size_t)row * XDIM + 1536 + k] = f2b(table[(size_t)trg[row] * E_DIM + k]);
}

// ----------------------------------------------- generic bf16 MFMA GEMM (NT)
__global__ __launch_bounds__(256) void gemm_bf16(
    const bfu* __restrict__ A0, int lda0, const bfu* __restrict__ W0, int ldw0,
    float* __restrict__ C0, int ldc0, const float* __restrict__ bias0, int K0,
    const bfu* __restrict__ A1, int lda1, const bfu* __restrict__ W1, int ldw1,
    float* __restrict__ C1, int ldc1, const float* __restrict__ bias1, int K1,
    int act, bfu* __restrict__ Cb0)
{
    const int z = blockIdx.z;
    const bfu* A = z ? A1 : A0;
    const bfu* W = z ? W1 : W0;
    float*     C = z ? C1 : C0;
    const float* bias = z ? bias1 : bias0;
    bfu*       Cb = z ? nullptr : Cb0;
    const int lda = z ? lda1 : lda0;
    const int ldw = z ? ldw1 : ldw0;
    const int ldc = z ? ldc1 : ldc0;
    const int K   = z ? K1 : K0;

    __shared__ short lds[2][2][4096];
    const int tid  = threadIdx.x;
    const int wid  = tid >> 6, lane = tid & 63;
    const int l15  = lane & 15, lk = lane >> 4;
    const int wr   = (wid >> 1) * 64, wc = (wid & 1) * 64;
    const size_t row0 = (size_t)blockIdx.y * 128;
    const size_t col0 = (size_t)blockIdx.x * 128;

    const int r0 = tid & 127, kc0 = tid >> 7;
    const int kc1 = kc0 + 2;
    const int sb0 = (wid * 64) * 16;
    const int sb1 = (wid * 64 + 256) * 16;

    f32x4 acc[4][4];
#pragma unroll
    for (int m = 0; m < 4; ++m)
#pragma unroll
        for (int n = 0; n < 4; ++n) acc[m][n] = (f32x4){0.f, 0.f, 0.f, 0.f};

    auto stage = [&](int buf, int kt) {
        char* ba = (char*)&lds[buf][0][0];
        char* bb = (char*)&lds[buf][1][0];
        GLDS(A + (row0 + r0) * (size_t)lda + kt + kc0 * 8, ba + sb0);
        GLDS(A + (row0 + r0) * (size_t)lda + kt + kc1 * 8, ba + sb1);
        GLDS(W + (col0 + r0) * (size_t)ldw + kt + kc0 * 8, bb + sb0);
        GLDS(W + (col0 + r0) * (size_t)ldw + kt + kc1 * 8, bb + sb1);
    };

    stage(0, 0);
    __syncthreads();
    const int nk = K >> 5;
    for (int t = 0; t < nk; ++t) {
        const int buf = t & 1;
        if (t + 1 < nk) stage(buf ^ 1, (t + 1) << 5);
        short8 af[4], bf_[4];
#pragma unroll
        for (int m = 0; m < 4; ++m)
            af[m] = *(const short8*)&lds[buf][0][lk * 1024 + (wr + m * 16 + l15) * 8];
#pragma unroll
        for (int n = 0; n < 4; ++n)
            bf_[n] = *(const short8*)&lds[buf][1][lk * 1024 + (wc + n * 16 + l15) * 8];
#pragma unroll
        for (int m = 0; m < 4; ++m)
#pragma unroll
            for (int n = 0; n < 4; ++n)
                acc[m][n] = MFMA16(af[m], bf_[n], acc[m][n]);
        __syncthreads();
    }

    float bv[4];
#pragma unroll
    for (int n = 0; n < 4; ++n)
        bv[n] = bias ? bias[col0 + wc + n * 16 + l15] : 0.f;
    const size_t crow = row0 + wr + lk * 4;
#pragma unroll
    for (int m = 0; m < 4; ++m) {
#pragma unroll
        for (int q = 0; q < 4; ++q) {
            const size_t r = crow + m * 16 + q;
            float* cp = C + r * ldc + col0 + wc + l15;
            bfu*   cb = Cb ? (Cb + r * ldc + col0 + wc + l15) : nullptr;
#pragma unroll
            for (int n = 0; n < 4; ++n) {
                float v = acc[m][n][q] + bv[n];
                if (act) v = ftanh(v);
                cp[n * 16] = v;
                if (Cb) cb[n * 16] = f2b(v);
            }
        }
    }
}

// ----------------------------------------------- big output GEMM, 256x256 tile
// Triple-buffered K pipeline: counted vmcnt(4) + single s_barrier per step.
// stage(t+2) issued AFTER the barrier (targets buffer read at t-1, whose reads
// all waves finished before passing the barrier). Loads get ~2 iters in flight.
__global__ __launch_bounds__(512) void gemm_big(
    const bfu* __restrict__ A, const bfu* __restrict__ W,
    float* __restrict__ C, const float* __restrict__ bias,
    bfu* __restrict__ Lb, int obf)
{
    __shared__ short lds[3][2][8192];   // 96 KB
    const int tid = threadIdx.x;
    const int wid = tid >> 6, lane = tid & 63;
    const int l15 = lane & 15, lk = lane >> 4;
    const int wr = (wid >> 2) * 128;
    const int wcc = (wid & 3) * 64;
    const int fid = blockIdx.x;          // 0..1999
    const int bx = fid >> 4, by = fid & 15;
    const size_t row0 = (size_t)by * 256;
    const size_t col0 = (size_t)bx * 256;

    f32x4 acc[8][4];
#pragma unroll
    for (int m = 0; m < 8; ++m)
#pragma unroll
        for (int n = 0; n < 4; ++n) acc[m][n] = (f32x4){0.f, 0.f, 0.f, 0.f};

    auto stage = [&](int buf, int kt) {
        char* ba = (char*)&lds[buf][0][0];
        char* bb = (char*)&lds[buf][1][0];
#pragma unroll
        for (int it = 0; it < 2; ++it) {
            int c = it * 512 + tid;
            int kc = c >> 8, row = c & 255;
            int base = (it * 512 + wid * 64) * 16;
            GLDS(A + (row0 + row) * (size_t)XDIM + kt + kc * 8, ba + base);
            GLDS(W + (col0 + row) * (size_t)XDIM + kt + kc * 8, bb + base);
        }
    };

    stage(0, 0);
    stage(1, 32);
    for (int t = 0; t < 56; ++t) {
        const int buf = t % 3;
        if (t < 55) { asm volatile("s_waitcnt vmcnt(4)" ::: "memory"); }
        else        { asm volatile("s_waitcnt vmcnt(0)" ::: "memory"); }
        __builtin_amdgcn_s_barrier();
        asm volatile("" ::: "memory");
        if (t + 2 < 56) stage((t + 2) % 3, (t + 2) * 32);
        short8 af[8], bf_[4];
#pragma unroll
        for (int m = 0; m < 8; ++m)
            af[m] = *(const short8*)&lds[buf][0][lk * 2048 + (wr + m * 16 + l15) * 8];
#pragma unroll
        for (int n = 0; n < 4; ++n)
            bf_[n] = *(const short8*)&lds[buf][1][lk * 2048 + (wcc + n * 16 + l15) * 8];
#pragma unroll
        for (int m = 0; m < 8; ++m)
#pragma unroll
            for (int n = 0; n < 4; ++n)
                acc[m][n] = MFMA16(af[m], bf_[n], acc[m][n]);
    }
    if (row0 + wr < 3968) {
        float bv[4];
#pragma unroll
        for (int n = 0; n < 4; ++n) bv[n] = bias[col0 + wcc + n * 16 + l15];
#pragma unroll
        for (int m = 0; m < 8; ++m) {
#pragma unroll
            for (int q = 0; q < 4; ++q) {
                const size_t r = row0 + wr + lk * 4 + m * 16 + q;
                if (obf) {
                    bfu* cp = Lb + r * VOCAB + col0 + wcc + l15;
#pragma unroll
                    for (int n = 0; n < 4; ++n) {
                        unsigned hb = f2b(acc[m][n][q] + bv[n]);
                        unsigned ot = (unsigned)__shfl_xor((int)hb, 1);
                        if ((lane & 1) == 0)
                            *(unsigned*)(cp + n * 16) = (hb & 0xffffu) | (ot << 16);
                    }
                } else {
                    float* cp = C + r * VOCAB + col0 + wcc + l15;
#pragma unroll
                    for (int n = 0; n < 4; ++n) cp[n * 16] = acc[m][n][q] + bv[n];
                }
            }
        }
    }
}

// ----------------------------------------------- fused encoder step (batch-split)
__global__ __launch_bounds__(256) void enc_step(
    const float* __restrict__ gi_f, const float* __restrict__ gi_b,
    const bfu* __restrict__ Whhf_b, const bfu* __restrict__ Whhb_b,
    const float* __restrict__ bhh_f, const float* __restrict__ bhh_b,
    const float* __restrict__ hin, float* __restrict__ hout,
    const bfu* __restrict__ hbin, bfu* __restrict__ hbout,
    bfu* __restrict__ encbt, int s)
{
    __shared__ short Bs[64 * 48 * 8];
    const int tid = threadIdx.x;
    const int wid = tid >> 6, lane = tid & 63;
    const int l15 = lane & 15, lk = lane >> 4;
    const int dir = blockIdx.z;
    const int u0 = blockIdx.x * 16;
    const int bb0 = blockIdx.y * 64;
    const int p = dir ? (S_LEN - 1 - s) : s;
    const bfu* Whh = dir ? Whhb_b : Whhf_b;
    const float* bhh = dir ? bhh_b : bhh_f;
    const float* gi = (dir ? gi_b : gi_f) + (size_t)p * BATCH * 1536;

    {
        char* bb = (char*)Bs;
#pragma unroll
        for (int it = 0; it < 12; ++it) {
            int c = it * 256 + tid;
            int r48 = c % 48, kc = c / 48;
            int wr = (r48 >> 4) * 512 + u0 + (r48 & 15);
            GLDS(Whh + (size_t)wr * 512 + kc * 8, bb + (it * 256 + wid * 64) * 16);
        }
    }
    __syncthreads();

    const bfu* ap0 = hbin + (size_t)(bb0 + wid * 16 + l15) * 1024 + dir * 512 + lk * 8;
    f32x4 acc[3];
#pragma unroll
    for (int g = 0; g < 3; ++g) acc[g] = (f32x4){0.f, 0.f, 0.f, 0.f};

#pragma unroll
    for (int kk = 0; kk < 16; ++kk) {
        short8 a0 = *(const short8*)(ap0 + kk * 32);
#pragma unroll
        for (int g = 0; g < 3; ++g) {
            short8 bf_ = *(const short8*)&Bs[((kk * 4 + lk) * 48 + g * 16 + l15) * 8];
            acc[g] = MFMA16(a0, bf_, acc[g]);
        }
    }

    const int u = u0 + l15;
    const float bR = bhh[u], bZ = bhh[512 + u], bN = bhh[1024 + u];
#pragma unroll
    for (int q = 0; q < 4; ++q) {
        const int b = bb0 + wid * 16 + lk * 4 + q;
        const float* gib = gi + (size_t)b * 1536;
        float rr = sigm(gib[u] + acc[0][q] + bR);
        float zz = sigm(gib[512 + u] + acc[1][q] + bZ);
        float nn = ftanh(gib[1024 + u] + rr * (acc[2][q] + bN));
        float h2 = (1.f - zz) * nn + zz * hin[(size_t)b * 1024 + dir * 512 + u];
        hout[(size_t)b * 1024 + dir * 512 + u] = h2;
        hbout[(size_t)b * 1024 + dir * 512 + u] = f2b(h2);
        encbt[((size_t)b * S_LEN + p) * 1024 + dir * 512 + u] = f2b(h2);
    }
}

// ----------------------------------------------- fused hp + attention step
__global__ __launch_bounds__(256) void attn_fused(
    const bfu* __restrict__ hb, const bfu* __restrict__ WahT,
    const bfu* __restrict__ encp_b, const bfu* __restrict__ encbt,
    const float* __restrict__ v_attn, const int* __restrict__ src,
    bfu* __restrict__ wbuf, bfu* __restrict__ Xb, int t)
{
    __shared__ float hls[512];
    __shared__ float vas[512];
    __shared__ float hps[512];
    __shared__ float sc[64];
    const int b = blockIdx.x, tid = threadIdx.x;
    for (int i = tid; i < 512; i += 256) {
        hls[i] = b2f(hb[(size_t)b * 512 + i]);
        vas[i] = v_attn[i];
    }
    __syncthreads();
    {
        const unsigned* wt = (const unsigned*)WahT;
        float a0 = 0.f, a1 = 0.f;
#pragma unroll 8
        for (int k = 0; k < 512; ++k) {
            unsigned w = wt[k * 256 + tid];
            float hk = hls[k];
            a0 += hk * __uint_as_float(w << 16);
            a1 += hk * __uint_as_float(w & 0xffff0000u);
        }
        hps[tid * 2]     = a0;
        hps[tid * 2 + 1] = a1;
    }
    __syncthreads();
    const int s = tid >> 2, l4 = tid & 3;
    const unsigned* epb = (const unsigned*)(encp_b + ((size_t)b * S_LEN + s) * 512);
    float part = 0.f;
#pragma unroll 4
    for (int dp = l4; dp < 256; dp += 4) {
        unsigned w = epb[dp];
        part += vas[2 * dp]     * ftanh(__uint_as_float(w << 16) + hps[2 * dp]);
        part += vas[2 * dp + 1] * ftanh(__uint_as_float(w & 0xffff0000u) + hps[2 * dp + 1]);
    }
    part += __shfl_xor(part, 1);
    part += __shfl_xor(part, 2);
    if (l4 == 0) sc[s] = (src[s * BATCH + b] != 0) ? part : -1e10f;
    __syncthreads();
    if (tid < 64) {
        float x = sc[tid], mx = x;
        for (int o = 1; o < 64; o <<= 1) mx = fmaxf(mx, __shfl_xor(mx, o));
        float e = expf(x - mx), s2 = e;
        for (int o = 1; o < 64; o <<= 1) s2 += __shfl_xor(s2, o);
        sc[tid] = e / s2;
    }
    __syncthreads();
    bfu* xw = Xb + ((size_t)t * BATCH + b) * XDIM + 512;
#pragma unroll
    for (int c = 0; c < 4; ++c) {
        int e = tid + 256 * c;
        float a2 = 0.f;
#pragma unroll 8
        for (int s2 = 0; s2 < S_LEN; ++s2) a2 += sc[s2] * b2f(encbt[((size_t)b * S_LEN + s2) * 1024 + e]);
        bfu v = f2b(a2);
        wbuf[(size_t)b * 1024 + e] = v;
        xw[e] = v;
    }
}

// ----------------------------------------------- fused decoder GEMM + gate (batch-split)
__global__ __launch_bounds__(256) void dec_step(
    const float* __restrict__ gie, const bfu* __restrict__ Whhd_b,
    const bfu* __restrict__ Wihd_b, const float* __restrict__ bhh_d,
    const bfu* __restrict__ hbin, const bfu* __restrict__ wbuf,
    const float* __restrict__ hin, float* __restrict__ hout,
    bfu* __restrict__ hbout, bfu* __restrict__ Xb, int t)
{
    __shared__ short Bh[64 * 48 * 8];
    __shared__ short Bw[128 * 48 * 8];
    const int tid = threadIdx.x;
    const int wid = tid >> 6, lane = tid & 63;
    const int l15 = lane & 15, lk = lane >> 4;
    const int u0 = blockIdx.x * 16;
    const int bb0 = blockIdx.y * 64;

    {
        char* bb = (char*)Bh;
#pragma unroll
        for (int it = 0; it < 12; ++it) {
            int c = it * 256 + tid;
            int r48 = c % 48, kc = c / 48;
            int wr = (r48 >> 4) * 512 + u0 + (r48 & 15);
            GLDS(Whhd_b + (size_t)wr * 512 + kc * 8, bb + (it * 256 + wid * 64) * 16);
        }
        char* bw = (char*)Bw;
#pragma unroll
        for (int it = 0; it < 24; ++it) {
            int c = it * 256 + tid;
            int r48 = c % 48, kc = c / 48;
            int wr = (r48 >> 4) * 512 + u0 + (r48 & 15);
            GLDS(Wihd_b + (size_t)wr * 1280 + 256 + kc * 8, bw + (it * 256 + wid * 64) * 16);
        }
    }
    __syncthreads();

    f32x4 accR, accZ, accNH, accNW;
    accR = (f32x4){0.f, 0.f, 0.f, 0.f};
    accZ = (f32x4){0.f, 0.f, 0.f, 0.f};
    accNH = (f32x4){0.f, 0.f, 0.f, 0.f};
    accNW = (f32x4){0.f, 0.f, 0.f, 0.f};

    {
        const bfu* ap0 = hbin + (size_t)(bb0 + wid * 16 + l15) * 512 + lk * 8;
#pragma unroll
        for (int kk = 0; kk < 16; ++kk) {
            short8 a0 = *(const short8*)(ap0 + kk * 32);
            short8 br = *(const short8*)&Bh[((kk * 4 + lk) * 48 + l15) * 8];
            short8 bz = *(const short8*)&Bh[((kk * 4 + lk) * 48 + 16 + l15) * 8];
            short8 bn = *(const short8*)&Bh[((kk * 4 + lk) * 48 + 32 + l15) * 8];
            accR = MFMA16(a0, br, accR);
            accZ = MFMA16(a0, bz, accZ);
            accNH = MFMA16(a0, bn, accNH);
        }
    }
    {
        const bfu* ap0 = wbuf + (size_t)(bb0 + wid * 16 + l15) * 1024 + lk * 8;
#pragma unroll
        for (int kk = 0; kk < 32; ++kk) {
            short8 a0 = *(const short8*)(ap0 + kk * 32);
            short8 br = *(const short8*)&Bw[((kk * 4 + lk) * 48 + l15) * 8];
            short8 bz = *(const short8*)&Bw[((kk * 4 + lk) * 48 + 16 + l15) * 8];
            short8 bn = *(const short8*)&Bw[((kk * 4 + lk) * 48 + 32 + l15) * 8];
            accR = MFMA16(a0, br, accR);
            accZ = MFMA16(a0, bz, accZ);
            accNW = MFMA16(a0, bn, accNW);
        }
    }

    const int u = u0 + l15;
    const float bR = bhh_d[u], bZ = bhh_d[512 + u], bN = bhh_d[1024 + u];
#pragma unroll
    for (int q = 0; q < 4; ++q) {
        const int b = bb0 + wid * 16 + lk * 4 + q;
        const float* geb = gie + ((size_t)t * BATCH + b) * 1536;
        float rr = sigm(geb[u] + accR[q] + bR);
        float zz = sigm(geb[512 + u] + accZ[q] + bZ);
        float nn = ftanh(geb[1024 + u] + accNW[q] + rr * (accNH[q] + bN));
        float h2 = (1.f - zz) * nn + zz * hin[(size_t)b * 512 + u];
        hout[(size_t)b * 512 + u] = h2;
        hbout[(size_t)b * 512 + u] = f2b(h2);
        Xb[((size_t)t * BATCH + b) * XDIM + u] = f2b(h2);
    }
}

// --------------------------- log-softmax (dual: bf16 logits or f32 in-place)
__global__ __launch_bounds__(256) void log_softmax_fill(
    const bfu* __restrict__ Lb, float* __restrict__ out, int obf)
{
    __shared__ float sm[256], ss[256];
    const int row = blockIdx.x;
    const int tid = threadIdx.x;
    float* po = out + (size_t)row * VOCAB;
    if (row >= 3968) {
        float4* p4 = (float4*)po;
        for (int i = tid; i < 8000; i += 256) {
            float4 v = {0.f, 0.f, 0.f, 0.f};
            if (i == 0) v.z = 100.f;     // EOS=2
            p4[i] = v;
        }
        return;
    }
    float m = -3.4e38f, ssum = 0.f;
    if (obf) {
        const uint4* pb = (const uint4*)(Lb + (size_t)row * VOCAB);
        for (int i = tid; i < 4000; i += 256) {
            uint4 w = pb[i];
            float x[8];
            x[0] = __uint_as_float(w.x << 16); x[1] = __uint_as_float(w.x & 0xffff0000u);
            x[2] = __uint_as_float(w.y << 16); x[3] = __uint_as_float(w.y & 0xffff0000u);
            x[4] = __uint_as_float(w.z << 16); x[5] = __uint_as_float(w.z & 0xffff0000u);
            x[6] = __uint_as_float(w.w << 16); x[7] = __uint_as_float(w.w & 0xffff0000u);
            float mx = x[0];
#pragma unroll
            for (int j = 1; j < 8; ++j) mx = fmaxf(mx, x[j]);
            float mn = fmaxf(m, mx);
            float e = 0.f;
#pragma unroll
            for (int j = 0; j < 8; ++j) e += expf(x[j] - mn);
            ssum = ssum * expf(m - mn) + e;
            m = mn;
        }
    } else {
        const float4* p4 = (const float4*)po;
        for (int i = tid; i < 8000; i += 256) {
            float4 v = p4[i];
            float mx = fmaxf(fmaxf(v.x, v.y), fmaxf(v.z, v.w));
            float mn = fmaxf(m, mx);
            ssum = ssum * expf(m - mn) + expf(v.x - mn) + expf(v.y - mn)
                 + expf(v.z - mn) + expf(v.w - mn);
            m = mn;
        }
    }
    sm[tid] = m; ss[tid] = ssum;
    __syncthreads();
    for (int off = 128; off > 0; off >>= 1) {
        if (tid < off) {
            float m2 = sm[tid + off], s2 = ss[tid + off];
            float M = fmaxf(sm[tid], m2);
            ss[tid] = ss[tid] * expf(sm[tid] - M) + s2 * expf(m2 - M);
            sm[tid] = M;
        }
        __syncthreads();
    }
    const float lse = sm[0] + logf(ss[0]);
    if (obf) {
        const uint4* pb = (const uint4*)(Lb + (size_t)row * VOCAB);
        float4* p4 = (float4*)po;
        for (int i = tid; i < 4000; i += 256) {
            uint4 w = pb[i];
            float4 a, b4;
            a.x = __uint_as_float(w.x << 16) - lse;
            a.y = __uint_as_float(w.x & 0xffff0000u) - lse;
            a.z = __uint_as_float(w.y << 16) - lse;
            a.w = __uint_as_float(w.y & 0xffff0000u) - lse;
            b4.x = __uint_as_float(w.z << 16) - lse;
            b4.y = __uint_as_float(w.z & 0xffff0000u) - lse;
            b4.z = __uint_as_float(w.w << 16) - lse;
            b4.w = __uint_as_float(w.w & 0xffff0000u) - lse;
            p4[i * 2] = a;
            p4[i * 2 + 1] = b4;
        }
    } else {
        float4* p4 = (float4*)po;
        for (int i = tid; i < 8000; i += 256) {
            float4 v = p4[i];
            v.x -= lse; v.y -= lse; v.z -= lse; v.w -= lse;
            p4[i] = v;
        }
    }
}

// ==================================================================== launch
extern "C" void kernel_launch(void* const* d_in, const int* in_sizes, int n_in,
                              void* d_out, int out_size, void* d_ws, size_t ws_size,
                              hipStream_t stream)
{
    const int*   src     = (const int*)d_in[0];
    const int*   trg     = (const int*)d_in[2];
    const float* emb_enc = (const float*)d_in[3];
    const float* emb_dec = (const float*)d_in[4];
    const float* Wih_f   = (const float*)d_in[5];
    const float* Whh_f   = (const float*)d_in[6];
    const float* bih_f   = (const float*)d_in[7];
    const float* bhh_f   = (const float*)d_in[8];
    const float* Wih_b   = (const float*)d_in[9];
    const float* Whh_b   = (const float*)d_in[10];
    const float* bih_b   = (const float*)d_in[11];
    const float* bhh_b   = (const float*)d_in[12];
    const float* W_fc    = (const float*)d_in[13];
    const float* b_fc    = (const float*)d_in[14];
    const float* W_attn  = (const float*)d_in[15];
    const float* b_attn  = (const float*)d_in[16];
    const float* v_attn  = (const float*)d_in[17];
    const float* Wih_d   = (const float*)d_in[18];
    const float* Whh_d   = (const float*)d_in[19];
    const float* bih_d   = (const float*)d_in[20];
    const float* bhh_d   = (const float*)d_in[21];
    const float* W_out   = (const float*)d_in[22];
    const float* b_out   = (const float*)d_in[23];
    float* out = (float*)d_out;

    char* wsb = (char*)d_ws;
    size_t off = 0;
    auto alloc = [&](size_t bytes) { void* q = wsb + off; off = (off + bytes + 255) & ~(size_t)255; return q; };
    bfu*   emb_b   = (bfu*)alloc((size_t)8192 * 256 * 2);
    bfu*   encbt_b = (bfu*)alloc((size_t)8192 * 1024 * 2);
    float* encp    = (float*)alloc((size_t)8192 * 512 * 4);
    bfu*   encp_b  = (bfu*)alloc((size_t)8192 * 512 * 2);
    float* gi_f    = (float*)alloc((size_t)8192 * 1536 * 4);
    float* gi_b    = (float*)alloc((size_t)8192 * 1536 * 4);
    float* gie     = (float*)alloc((size_t)3968 * 1536 * 4);
    bfu*   wbuf    = (bfu*)alloc((size_t)128 * 1024 * 2);
    float* hA      = (float*)alloc((size_t)128 * 1024 * 4);
    float* hB      = (float*)alloc((size_t)128 * 1024 * 4);
    bfu*   hbA     = (bfu*)alloc((size_t)128 * 1024 * 2);
    bfu*   hbB     = (bfu*)alloc((size_t)128 * 1024 * 2);
    float* hdA     = (float*)alloc((size_t)128 * 512 * 4);
    float* hdB     = (float*)alloc((size_t)128 * 512 * 4);
    bfu*   hdbA    = (bfu*)alloc((size_t)128 * 512 * 2);
    bfu*   hdbB    = (bfu*)alloc((size_t)128 * 512 * 2);
    bfu*   Xb      = (bfu*)alloc((size_t)MPAD * XDIM * 2);
    bfu*   Wihf_b  = (bfu*)alloc((size_t)1536 * 256 * 2);
    bfu*   Wihb_b  = (bfu*)alloc((size_t)1536 * 256 * 2);
    bfu*   Whhf_b  = (bfu*)alloc((size_t)1536 * 512 * 2);
    bfu*   Whhb_b  = (bfu*)alloc((size_t)1536 * 512 * 2);
    bfu*   Wfc_b   = (bfu*)alloc((size_t)512 * 1024 * 2);
    bfu*   Wattn_b = (bfu*)alloc((size_t)512 * 1536 * 2);
    bfu*   WahT    = (bfu*)alloc((size_t)512 * 512 * 2);
    bfu*   Wihd_b  = (bfu*)alloc((size_t)1536 * 1280 * 2);
    bfu*   Whhd_b  = (bfu*)alloc((size_t)1536 * 512 * 2);
    bfu*   Wout_b  = (bfu*)alloc((size_t)VOCAB * XDIM * 2);

    const size_t lb_bytes = (size_t)MPAD * VOCAB * 2;
    bfu* Lb = nullptr;
    if (ws_size >= off + lb_bytes + 256) Lb = (bfu*)alloc(lb_bytes);
    const int obf = (Lb != nullptr) ? 1 : 0;

    conv_all<<<(15941632 + 255) / 256, 256, 0, stream>>>(
        Wih_f, Wih_b, Whh_f, Whh_b, W_fc, W_attn, Wih_d, Whh_d, W_out,
        Wihf_b, Wihb_b, Whhf_b, Whhb_b, Wfc_b, Wattn_b, Wihd_b, Whhd_b, Wout_b);
    transpose_wah<<<1024, 256, 0, stream>>>(W_attn, WahT);

    gather_emb<<<(8192 * 256 + 255) / 256, 256, 0, stream>>>(emb_enc, src, emb_b, 8192 * 256);
    gather_trg<<<(3968 * 256 + 255) / 256, 256, 0, stream>>>(emb_dec, trg, Xb, 3968 * 256);
    zero_kernel<<<(131072 + 255) / 256, 256, 0, stream>>>(hA, 131072);
    zero_kernel<<<(65536 + 255) / 256, 256, 0, stream>>>((float*)hbA, 65536);

    // gi for all encoder steps, both dirs
    gemm_bf16<<<dim3(12, 64, 2), 256, 0, stream>>>(
        emb_b, 256, Wihf_b, 256, gi_f, 1536, bih_f, 256,
        emb_b, 256, Wihb_b, 256, gi_b, 1536, bih_b, 256, 0, nullptr);
    // gi_e for all decoder steps
    gemm_bf16<<<dim3(12, 31, 1), 256, 0, stream>>>(
        Xb + 1536, XDIM, Wihd_b, 1280, gie, 1536, bih_d, 256,
        Xb + 1536, XDIM, Wihd_b, 1280, gie, 1536, bih_d, 256, 0, nullptr);

    // encoder: 64 fused steps (batch-split grid)
    for (int s = 0; s < S_LEN; ++s) {
        const float* hin  = (s & 1) ? hB : hA;
        float*       hout = (s & 1) ? hA : hB;
        const bfu*   hbin = (s & 1) ? hbB : hbA;
        bfu*         hbout = (s & 1) ? hbA : hbB;
        enc_step<<<dim3(32, 2, 2), 256, 0, stream>>>(
            gi_f, gi_b, Whhf_b, Whhb_b, bhh_f, bhh_b,
            hin, hout, hbin, hbout, encbt_b, s);
    }
    // hid = tanh([hf,hb] @ W_fc^T + b_fc)
    gemm_bf16<<<dim3(4, 1, 1), 256, 0, stream>>>(
        hbA, 1024, Wfc_b, 1024, hdA, 512, b_fc, 1024,
        hbA, 1024, Wfc_b, 1024, hdA, 512, b_fc, 1024, 1, hdbA);
    // enc_proj (f32 + bf16 mirror)
    gemm_bf16<<<dim3(4, 64, 1), 256, 0, stream>>>(
        encbt_b, 1024, Wattn_b + 512, 1536, encp, 512, b_attn, 1024,
        encbt_b, 1024, Wattn_b + 512, 1536, encp, 512, b_attn, 1024, 0, encp_b);

    // decoder: 31 steps x 2 launches
    for (int t = 0; t < T_LEN - 1; ++t) {
        const float* hin  = (t & 1) ? hdB : hdA;
        float*       hout = (t & 1) ? hdA : hdB;
        const bfu*   hbin = (t & 1) ? hdbB : hdbA;
        bfu*         hbout = (t & 1) ? hdbA : hdbB;
        attn_fused<<<BATCH, 256, 0, stream>>>(hbin, WahT, encp_b, encbt_b,
                                              v_attn, src, wbuf, Xb, t);
        dec_step<<<dim3(32, 2), 256, 0, stream>>>(
            gie, Whhd_b, Wihd_b, bhh_d, hbin, wbuf, hin, hout, hbout, Xb, t);
    }

    // logits (bf16 if room) + log-softmax + fill plane
    gemm_big<<<dim3(2000, 1), 512, 0, stream>>>(Xb, Wout_b, out, b_out, Lb, obf);
    log_softmax_fill<<<4096, 256, 0, stream>>>(Lb, out, obf);
}

// Round 17
// 3706.267 us; speedup vs baseline: 1.0370x; 1.0010x over previous
//
#include <hip/hip_runtime.h>
#include <cstddef>
#include <cstdint>

#define S_LEN 64
#define BATCH 128
#define T_LEN 32
#define E_DIM 256
#define VOCAB 32000
#define XDIM 1792
#define MPAD 4096

typedef unsigned short bfu;
typedef short short8 __attribute__((ext_vector_type(8)));
typedef float f32x4 __attribute__((ext_vector_type(4)));

__device__ __forceinline__ bfu f2b(float f) {
    unsigned int x = __float_as_uint(f);
    x += 0x7fffu + ((x >> 16) & 1u);
    return (bfu)(x >> 16);
}
__device__ __forceinline__ float b2f(bfu u) { return __uint_as_float(((unsigned)u) << 16); }
__device__ __forceinline__ f32x4 MFMA16(short8 a, short8 b, f32x4 c) {
    return __builtin_amdgcn_mfma_f32_16x16x32_bf16(a, b, c, 0, 0, 0);
}
__device__ __forceinline__ float sigm(float x) {
    return 1.f / (1.f + exp2f(x * -1.4426950408889634f));
}
__device__ __forceinline__ float ftanh(float x) {
    float xc = fminf(15.f, fmaxf(-15.f, x));
    float t = exp2f(xc * 2.8853900817779268f);
    return (t - 1.f) / (t + 1.f);
}

#define GLDS(gsrc, ldst)                                                       \
    __builtin_amdgcn_global_load_lds(                                          \
        (const __attribute__((address_space(1))) void*)(gsrc),                 \
        (__attribute__((address_space(3))) void*)(ldst), 16, 0, 0)

// ---------------------------------------------------------------- utilities
__global__ void zero_kernel(float* __restrict__ p, int n) {
    int i = blockIdx.x * 256 + threadIdx.x;
    if (i < n) p[i] = 0.f;
}

__global__ void conv_all(
    const float* __restrict__ s0, const float* __restrict__ s1,
    const float* __restrict__ s2, const float* __restrict__ s3,
    const float* __restrict__ s4, const float* __restrict__ s5,
    const float* __restrict__ s6, const float* __restrict__ s7,
    const float* __restrict__ s8,
    bfu* __restrict__ d0, bfu* __restrict__ d1, bfu* __restrict__ d2,
    bfu* __restrict__ d3, bfu* __restrict__ d4, bfu* __restrict__ d5,
    bfu* __restrict__ d6, bfu* __restrict__ d7, bfu* __restrict__ d8)
{
    int i = blockIdx.x * 256 + threadIdx.x;
    if (i >= 15941632) return;
    const float* s; bfu* d; int base;
    if      (i <   98304) { s = s0; d = d0; base = 0; }
    else if (i <  196608) { s = s1; d = d1; base = 98304; }
    else if (i <  393216) { s = s2; d = d2; base = 196608; }
    else if (i <  589824) { s = s3; d = d3; base = 393216; }
    else if (i <  720896) { s = s4; d = d4; base = 589824; }
    else if (i <  917504) { s = s5; d = d5; base = 720896; }
    else if (i < 1409024) { s = s6; d = d6; base = 917504; }
    else if (i < 1605632) { s = s7; d = d7; base = 1409024; }
    else                  { s = s8; d = d8; base = 1605632; }
    int j = i - base;
    float4 v = ((const float4*)s)[j];
    ushort4 o;
    o.x = f2b(v.x); o.y = f2b(v.y); o.z = f2b(v.z); o.w = f2b(v.w);
    ((ushort4*)d)[j] = o;
}

// WahT[k][j] = bf16(W_attn[j][k])
__global__ void transpose_wah(const float* __restrict__ W_attn, bfu* __restrict__ WahT) {
    int i = blockIdx.x * 256 + threadIdx.x;
    if (i >= 262144) return;
    int k = i >> 9, j = i & 511;
    WahT[i] = f2b(W_attn[(size_t)j * 1536 + k]);
}

__global__ void gather_emb(const float* __restrict__ table, const int* __restrict__ idx,
                           bfu* __restrict__ out, int total) {
    int i = blockIdx.x * 256 + threadIdx.x;
    if (i >= total) return;
    int row = i >> 8, k = i & 255;
    out[i] = f2b(table[(size_t)idx[row] * E_DIM + k]);
}

__global__ void gather_trg(const float* __restrict__ table, const int* __restrict__ trg,
                           bfu* __restrict__ Xb, int total) {
    int i = blockIdx.x * 256 + threadIdx.x;
    if (i >= total) return;
    int row = i >> 8, k = i & 255;
    Xb[(size_t)row * XDIM + 1536 + k] = f2b(table[(size_t)trg[row] * E_DIM + k]);
}

// ----------------------------------------------- generic bf16 MFMA GEMM (NT)
__global__ __launch_bounds__(256) void gemm_bf16(
    const bfu* __restrict__ A0, int lda0, const bfu* __restrict__ W0, int ldw0,
    float* __restrict__ C0, int ldc0, const float* __restrict__ bias0, int K0,
    const bfu* __restrict__ A1, int lda1, const bfu* __restrict__ W1, int ldw1,
    float* __restrict__ C1, int ldc1, const float* __restrict__ bias1, int K1,
    int act, bfu* __restrict__ Cb0)
{
    const int z = blockIdx.z;
    const bfu* A = z ? A1 : A0;
    const bfu* W = z ? W1 : W0;
    float*     C = z ? C1 : C0;
    const float* bias = z ? bias1 : bias0;
    bfu*       Cb = z ? nullptr : Cb0;
    const int lda = z ? lda1 : lda0;
    const int ldw = z ? ldw1 : ldw0;
    const int ldc = z ? ldc1 : ldc0;
    const int K   = z ? K1 : K0;

    __shared__ short lds[2][2][4096];
    const int tid  = threadIdx.x;
    const int wid  = tid >> 6, lane = tid & 63;
    const int l15  = lane & 15, lk = lane >> 4;
    const int wr   = (wid >> 1) * 64, wc = (wid & 1) * 64;
    const size_t row0 = (size_t)blockIdx.y * 128;
    const size_t col0 = (size_t)blockIdx.x * 128;

    const int r0 = tid & 127, kc0 = tid >> 7;
    const int kc1 = kc0 + 2;
    const int sb0 = (wid * 64) * 16;
    const int sb1 = (wid * 64 + 256) * 16;

    f32x4 acc[4][4];
#pragma unroll
    for (int m = 0; m < 4; ++m)
#pragma unroll
        for (int n = 0; n < 4; ++n) acc[m][n] = (f32x4){0.f, 0.f, 0.f, 0.f};

    auto stage = [&](int buf, int kt) {
        char* ba = (char*)&lds[buf][0][0];
        char* bb = (char*)&lds[buf][1][0];
        GLDS(A + (row0 + r0) * (size_t)lda + kt + kc0 * 8, ba + sb0);
        GLDS(A + (row0 + r0) * (size_t)lda + kt + kc1 * 8, ba + sb1);
        GLDS(W + (col0 + r0) * (size_t)ldw + kt + kc0 * 8, bb + sb0);
        GLDS(W + (col0 + r0) * (size_t)ldw + kt + kc1 * 8, bb + sb1);
    };

    stage(0, 0);
    __syncthreads();
    const int nk = K >> 5;
    for (int t = 0; t < nk; ++t) {
        const int buf = t & 1;
        if (t + 1 < nk) stage(buf ^ 1, (t + 1) << 5);
        short8 af[4], bf_[4];
#pragma unroll
        for (int m = 0; m < 4; ++m)
            af[m] = *(const short8*)&lds[buf][0][lk * 1024 + (wr + m * 16 + l15) * 8];
#pragma unroll
        for (int n = 0; n < 4; ++n)
            bf_[n] = *(const short8*)&lds[buf][1][lk * 1024 + (wc + n * 16 + l15) * 8];
#pragma unroll
        for (int m = 0; m < 4; ++m)
#pragma unroll
            for (int n = 0; n < 4; ++n)
                acc[m][n] = MFMA16(af[m], bf_[n], acc[m][n]);
        __syncthreads();
    }

    float bv[4];
#pragma unroll
    for (int n = 0; n < 4; ++n)
        bv[n] = bias ? bias[col0 + wc + n * 16 + l15] : 0.f;
    const size_t crow = row0 + wr + lk * 4;
#pragma unroll
    for (int m = 0; m < 4; ++m) {
#pragma unroll
        for (int q = 0; q < 4; ++q) {
            const size_t r = crow + m * 16 + q;
            float* cp = C + r * ldc + col0 + wc + l15;
            bfu*   cb = Cb ? (Cb + r * ldc + col0 + wc + l15) : nullptr;
#pragma unroll
            for (int n = 0; n < 4; ++n) {
                float v = acc[m][n][q] + bv[n];
                if (act) v = ftanh(v);
                cp[n * 16] = v;
                if (Cb) cb[n * 16] = f2b(v);
            }
        }
    }
}

// ----------------------------------------------- big output GEMM, 256x256 tile
// Quad-buffered K pipeline (128KB LDS, 1 block/CU): counted vmcnt(8), single
// barrier per step, stage(t+3) after barrier (targets buffer read at t-1).
// In-order vmcnt completion => wait ladder: t<54 vmcnt(8), t==54 vmcnt(4),
// t==55 vmcnt(0). Each stage gets ~3 iterations of latency cover.
__global__ __launch_bounds__(512) void gemm_big(
    const bfu* __restrict__ A, const bfu* __restrict__ W,
    float* __restrict__ C, const float* __restrict__ bias,
    bfu* __restrict__ Lb, int obf)
{
    __shared__ short lds[4][2][8192];   // 128 KB
    const int tid = threadIdx.x;
    const int wid = tid >> 6, lane = tid & 63;
    const int l15 = lane & 15, lk = lane >> 4;
    const int wr = (wid >> 2) * 128;
    const int wcc = (wid & 3) * 64;
    const int fid = blockIdx.x;          // 0..1999
    const int bx = fid >> 4, by = fid & 15;
    const size_t row0 = (size_t)by * 256;
    const size_t col0 = (size_t)bx * 256;

    f32x4 acc[8][4];
#pragma unroll
    for (int m = 0; m < 8; ++m)
#pragma unroll
        for (int n = 0; n < 4; ++n) acc[m][n] = (f32x4){0.f, 0.f, 0.f, 0.f};

    auto stage = [&](int buf, int kt) {
        char* ba = (char*)&lds[buf][0][0];
        char* bb = (char*)&lds[buf][1][0];
#pragma unroll
        for (int it = 0; it < 2; ++it) {
            int c = it * 512 + tid;
            int kc = c >> 8, row = c & 255;
            int base = (it * 512 + wid * 64) * 16;
            GLDS(A + (row0 + row) * (size_t)XDIM + kt + kc * 8, ba + base);
            GLDS(W + (col0 + row) * (size_t)XDIM + kt + kc * 8, bb + base);
        }
    };

    stage(0, 0);
    stage(1, 32);
    stage(2, 64);
    for (int t = 0; t < 56; ++t) {
        const int buf = t & 3;
        if (t < 54)      { asm volatile("s_waitcnt vmcnt(8)" ::: "memory"); }
        else if (t < 55) { asm volatile("s_waitcnt vmcnt(4)" ::: "memory"); }
        else             { asm volatile("s_waitcnt vmcnt(0)" ::: "memory"); }
        __builtin_amdgcn_s_barrier();
        asm volatile("" ::: "memory");
        if (t + 3 < 56) stage((t + 3) & 3, (t + 3) * 32);
        short8 af[8], bf_[4];
#pragma unroll
        for (int m = 0; m < 8; ++m)
            af[m] = *(const short8*)&lds[buf][0][lk * 2048 + (wr + m * 16 + l15) * 8];
#pragma unroll
        for (int n = 0; n < 4; ++n)
            bf_[n] = *(const short8*)&lds[buf][1][lk * 2048 + (wcc + n * 16 + l15) * 8];
#pragma unroll
        for (int m = 0; m < 8; ++m)
#pragma unroll
            for (int n = 0; n < 4; ++n)
                acc[m][n] = MFMA16(af[m], bf_[n], acc[m][n]);
    }
    if (row0 + wr < 3968) {
        float bv[4];
#pragma unroll
        for (int n = 0; n < 4; ++n) bv[n] = bias[col0 + wcc + n * 16 + l15];
#pragma unroll
        for (int m = 0; m < 8; ++m) {
#pragma unroll
            for (int q = 0; q < 4; ++q) {
                const size_t r = row0 + wr + lk * 4 + m * 16 + q;
                if (obf) {
                    bfu* cp = Lb + r * VOCAB + col0 + wcc + l15;
#pragma unroll
                    for (int n = 0; n < 4; ++n) {
                        unsigned hb = f2b(acc[m][n][q] + bv[n]);
                        unsigned ot = (unsigned)__shfl_xor((int)hb, 1);
                        if ((lane & 1) == 0)
                            *(unsigned*)(cp + n * 16) = (hb & 0xffffu) | (ot << 16);
                    }
                } else {
                    float* cp = C + r * VOCAB + col0 + wcc + l15;
#pragma unroll
                    for (int n = 0; n < 4; ++n) cp[n * 16] = acc[m][n][q] + bv[n];
                }
            }
        }
    }
}

// ----------------------------------------------- fused encoder step (batch-split)
__global__ __launch_bounds__(256) void enc_step(
    const float* __restrict__ gi_f, const float* __restrict__ gi_b,
    const bfu* __restrict__ Whhf_b, const bfu* __restrict__ Whhb_b,
    const float* __restrict__ bhh_f, const float* __restrict__ bhh_b,
    const float* __restrict__ hin, float* __restrict__ hout,
    const bfu* __restrict__ hbin, bfu* __restrict__ hbout,
    bfu* __restrict__ encbt, int s)
{
    __shared__ short Bs[64 * 48 * 8];
    const int tid = threadIdx.x;
    const int wid = tid >> 6, lane = tid & 63;
    const int l15 = lane & 15, lk = lane >> 4;
    const int dir = blockIdx.z;
    const int u0 = blockIdx.x * 16;
    const int bb0 = blockIdx.y * 64;
    const int p = dir ? (S_LEN - 1 - s) : s;
    const bfu* Whh = dir ? Whhb_b : Whhf_b;
    const float* bhh = dir ? bhh_b : bhh_f;
    const float* gi = (dir ? gi_b : gi_f) + (size_t)p * BATCH * 1536;

    {
        char* bb = (char*)Bs;
#pragma unroll
        for (int it = 0; it < 12; ++it) {
            int c = it * 256 + tid;
            int r48 = c % 48, kc = c / 48;
            int wr = (r48 >> 4) * 512 + u0 + (r48 & 15);
            GLDS(Whh + (size_t)wr * 512 + kc * 8, bb + (it * 256 + wid * 64) * 16);
        }
    }
    __syncthreads();

    const bfu* ap0 = hbin + (size_t)(bb0 + wid * 16 + l15) * 1024 + dir * 512 + lk * 8;
    f32x4 acc[3];
#pragma unroll
    for (int g = 0; g < 3; ++g) acc[g] = (f32x4){0.f, 0.f, 0.f, 0.f};

#pragma unroll
    for (int kk = 0; kk < 16; ++kk) {
        short8 a0 = *(const short8*)(ap0 + kk * 32);
#pragma unroll
        for (int g = 0; g < 3; ++g) {
            short8 bf_ = *(const short8*)&Bs[((kk * 4 + lk) * 48 + g * 16 + l15) * 8];
            acc[g] = MFMA16(a0, bf_, acc[g]);
        }
    }

    const int u = u0 + l15;
    const float bR = bhh[u], bZ = bhh[512 + u], bN = bhh[1024 + u];
#pragma unroll
    for (int q = 0; q < 4; ++q) {
        const int b = bb0 + wid * 16 + lk * 4 + q;
        const float* gib = gi + (size_t)b * 1536;
        float rr = sigm(gib[u] + acc[0][q] + bR);
        float zz = sigm(gib[512 + u] + acc[1][q] + bZ);
        float nn = ftanh(gib[1024 + u] + rr * (acc[2][q] + bN));
        float h2 = (1.f - zz) * nn + zz * hin[(size_t)b * 1024 + dir * 512 + u];
        hout[(size_t)b * 1024 + dir * 512 + u] = h2;
        hbout[(size_t)b * 1024 + dir * 512 + u] = f2b(h2);
        encbt[((size_t)b * S_LEN + p) * 1024 + dir * 512 + u] = f2b(h2);
    }
}

// ----------------------------------------------- fused hp + attention step
__global__ __launch_bounds__(256) void attn_fused(
    const bfu* __restrict__ hb, const bfu* __restrict__ WahT,
    const bfu* __restrict__ encp_b, const bfu* __restrict__ encbt,
    const float* __restrict__ v_attn, const int* __restrict__ src,
    bfu* __restrict__ wbuf, bfu* __restrict__ Xb, int t)
{
    __shared__ float hls[512];
    __shared__ float vas[512];
    __shared__ float hps[512];
    __shared__ float sc[64];
    const int b = blockIdx.x, tid = threadIdx.x;
    for (int i = tid; i < 512; i += 256) {
        hls[i] = b2f(hb[(size_t)b * 512 + i]);
        vas[i] = v_attn[i];
    }
    __syncthreads();
    {
        const unsigned* wt = (const unsigned*)WahT;
        float a0 = 0.f, a1 = 0.f;
#pragma unroll 8
        for (int k = 0; k < 512; ++k) {
            unsigned w = wt[k * 256 + tid];
            float hk = hls[k];
            a0 += hk * __uint_as_float(w << 16);
            a1 += hk * __uint_as_float(w & 0xffff0000u);
        }
        hps[tid * 2]     = a0;
        hps[tid * 2 + 1] = a1;
    }
    __syncthreads();
    const int s = tid >> 2, l4 = tid & 3;
    const unsigned* epb = (const unsigned*)(encp_b + ((size_t)b * S_LEN + s) * 512);
    float part = 0.f;
#pragma unroll 4
    for (int dp = l4; dp < 256; dp += 4) {
        unsigned w = epb[dp];
        part += vas[2 * dp]     * ftanh(__uint_as_float(w << 16) + hps[2 * dp]);
        part += vas[2 * dp + 1] * ftanh(__uint_as_float(w & 0xffff0000u) + hps[2 * dp + 1]);
    }
    part += __shfl_xor(part, 1);
    part += __shfl_xor(part, 2);
    if (l4 == 0) sc[s] = (src[s * BATCH + b] != 0) ? part : -1e10f;
    __syncthreads();
    if (tid < 64) {
        float x = sc[tid], mx = x;
        for (int o = 1; o < 64; o <<= 1) mx = fmaxf(mx, __shfl_xor(mx, o));
        float e = expf(x - mx), s2 = e;
        for (int o = 1; o < 64; o <<= 1) s2 += __shfl_xor(s2, o);
        sc[tid] = e / s2;
    }
    __syncthreads();
    bfu* xw = Xb + ((size_t)t * BATCH + b) * XDIM + 512;
#pragma unroll
    for (int c = 0; c < 4; ++c) {
        int e = tid + 256 * c;
        float a2 = 0.f;
#pragma unroll 8
        for (int s2 = 0; s2 < S_LEN; ++s2) a2 += sc[s2] * b2f(encbt[((size_t)b * S_LEN + s2) * 1024 + e]);
        bfu v = f2b(a2);
        wbuf[(size_t)b * 1024 + e] = v;
        xw[e] = v;
    }
}

// ----------------------------------------------- fused decoder GEMM + gate (batch-split)
__global__ __launch_bounds__(256) void dec_step(
    const float* __restrict__ gie, const bfu* __restrict__ Whhd_b,
    const bfu* __restrict__ Wihd_b, const float* __restrict__ bhh_d,
    const bfu* __restrict__ hbin, const bfu* __restrict__ wbuf,
    const float* __restrict__ hin, float* __restrict__ hout,
    bfu* __restrict__ hbout, bfu* __restrict__ Xb, int t)
{
    __shared__ short Bh[64 * 48 * 8];
    __shared__ short Bw[128 * 48 * 8];
    const int tid = threadIdx.x;
    const int wid = tid >> 6, lane = tid & 63;
    const int l15 = lane & 15, lk = lane >> 4;
    const int u0 = blockIdx.x * 16;
    const int bb0 = blockIdx.y * 64;

    {
        char* bb = (char*)Bh;
#pragma unroll
        for (int it = 0; it < 12; ++it) {
            int c = it * 256 + tid;
            int r48 = c % 48, kc = c / 48;
            int wr = (r48 >> 4) * 512 + u0 + (r48 & 15);
            GLDS(Whhd_b + (size_t)wr * 512 + kc * 8, bb + (it * 256 + wid * 64) * 16);
        }
        char* bw = (char*)Bw;
#pragma unroll
        for (int it = 0; it < 24; ++it) {
            int c = it * 256 + tid;
            int r48 = c % 48, kc = c / 48;
            int wr = (r48 >> 4) * 512 + u0 + (r48 & 15);
            GLDS(Wihd_b + (size_t)wr * 1280 + 256 + kc * 8, bw + (it * 256 + wid * 64) * 16);
        }
    }
    __syncthreads();

    f32x4 accR, accZ, accNH, accNW;
    accR = (f32x4){0.f, 0.f, 0.f, 0.f};
    accZ = (f32x4){0.f, 0.f, 0.f, 0.f};
    accNH = (f32x4){0.f, 0.f, 0.f, 0.f};
    accNW = (f32x4){0.f, 0.f, 0.f, 0.f};

    {
        const bfu* ap0 = hbin + (size_t)(bb0 + wid * 16 + l15) * 512 + lk * 8;
#pragma unroll
        for (int kk = 0; kk < 16; ++kk) {
            short8 a0 = *(const short8*)(ap0 + kk * 32);
            short8 br = *(const short8*)&Bh[((kk * 4 + lk) * 48 + l15) * 8];
            short8 bz = *(const short8*)&Bh[((kk * 4 + lk) * 48 + 16 + l15) * 8];
            short8 bn = *(const short8*)&Bh[((kk * 4 + lk) * 48 + 32 + l15) * 8];
            accR = MFMA16(a0, br, accR);
            accZ = MFMA16(a0, bz, accZ);
            accNH = MFMA16(a0, bn, accNH);
        }
    }
    {
        const bfu* ap0 = wbuf + (size_t)(bb0 + wid * 16 + l15) * 1024 + lk * 8;
#pragma unroll
        for (int kk = 0; kk < 32; ++kk) {
            short8 a0 = *(const short8*)(ap0 + kk * 32);
            short8 br = *(const short8*)&Bw[((kk * 4 + lk) * 48 + l15) * 8];
            short8 bz = *(const short8*)&Bw[((kk * 4 + lk) * 48 + 16 + l15) * 8];
            short8 bn = *(const short8*)&Bw[((kk * 4 + lk) * 48 + 32 + l15) * 8];
            accR = MFMA16(a0, br, accR);
            accZ = MFMA16(a0, bz, accZ);
            accNW = MFMA16(a0, bn, accNW);
        }
    }

    const int u = u0 + l15;
    const float bR = bhh_d[u], bZ = bhh_d[512 + u], bN = bhh_d[1024 + u];
#pragma unroll
    for (int q = 0; q < 4; ++q) {
        const int b = bb0 + wid * 16 + lk * 4 + q;
        const float* geb = gie + ((size_t)t * BATCH + b) * 1536;
        float rr = sigm(geb[u] + accR[q] + bR);
        float zz = sigm(geb[512 + u] + accZ[q] + bZ);
        float nn = ftanh(geb[1024 + u] + accNW[q] + rr * (accNH[q] + bN));
        float h2 = (1.f - zz) * nn + zz * hin[(size_t)b * 512 + u];
        hout[(size_t)b * 512 + u] = h2;
        hbout[(size_t)b * 512 + u] = f2b(h2);
        Xb[((size_t)t * BATCH + b) * XDIM + u] = f2b(h2);
    }
}

// --------------------------- log-softmax (dual: bf16 logits or f32 in-place)
__global__ __launch_bounds__(256) void log_softmax_fill(
    const bfu* __restrict__ Lb, float* __restrict__ out, int obf)
{
    __shared__ float sm[256], ss[256];
    const int row = blockIdx.x;
    const int tid = threadIdx.x;
    float* po = out + (size_t)row * VOCAB;
    if (row >= 3968) {
        float4* p4 = (float4*)po;
        for (int i = tid; i < 8000; i += 256) {
            float4 v = {0.f, 0.f, 0.f, 0.f};
            if (i == 0) v.z = 100.f;     // EOS=2
            p4[i] = v;
        }
        return;
    }
    float m = -3.4e38f, ssum = 0.f;
    if (obf) {
        const uint4* pb = (const uint4*)(Lb + (size_t)row * VOCAB);
        for (int i = tid; i < 4000; i += 256) {
            uint4 w = pb[i];
            float x[8];
            x[0] = __uint_as_float(w.x << 16); x[1] = __uint_as_float(w.x & 0xffff0000u);
            x[2] = __uint_as_float(w.y << 16); x[3] = __uint_as_float(w.y & 0xffff0000u);
            x[4] = __uint_as_float(w.z << 16); x[5] = __uint_as_float(w.z & 0xffff0000u);
            x[6] = __uint_as_float(w.w << 16); x[7] = __uint_as_float(w.w & 0xffff0000u);
            float mx = x[0];
#pragma unroll
            for (int j = 1; j < 8; ++j) mx = fmaxf(mx, x[j]);
            float mn = fmaxf(m, mx);
            float e = 0.f;
#pragma unroll
            for (int j = 0; j < 8; ++j) e += expf(x[j] - mn);
            ssum = ssum * expf(m - mn) + e;
            m = mn;
        }
    } else {
        const float4* p4 = (const float4*)po;
        for (int i = tid; i < 8000; i += 256) {
            float4 v = p4[i];
            float mx = fmaxf(fmaxf(v.x, v.y), fmaxf(v.z, v.w));
            float mn = fmaxf(m, mx);
            ssum = ssum * expf(m - mn) + expf(v.x - mn) + expf(v.y - mn)
                 + expf(v.z - mn) + expf(v.w - mn);
            m = mn;
        }
    }
    sm[tid] = m; ss[tid] = ssum;
    __syncthreads();
    for (int off = 128; off > 0; off >>= 1) {
        if (tid < off) {
            float m2 = sm[tid + off], s2 = ss[tid + off];
            float M = fmaxf(sm[tid], m2);
            ss[tid] = ss[tid] * expf(sm[tid] - M) + s2 * expf(m2 - M);
            sm[tid] = M;
        }
        __syncthreads();
    }
    const float lse = sm[0] + logf(ss[0]);
    if (obf) {
        const uint4* pb = (const uint4*)(Lb + (size_t)row * VOCAB);
        float4* p4 = (float4*)po;
        for (int i = tid; i < 4000; i += 256) {
            uint4 w = pb[i];
            float4 a, b4;
            a.x = __uint_as_float(w.x << 16) - lse;
            a.y = __uint_as_float(w.x & 0xffff0000u) - lse;
            a.z = __uint_as_float(w.y << 16) - lse;
            a.w = __uint_as_float(w.y & 0xffff0000u) - lse;
            b4.x = __uint_as_float(w.z << 16) - lse;
            b4.y = __uint_as_float(w.z & 0xffff0000u) - lse;
            b4.z = __uint_as_float(w.w << 16) - lse;
            b4.w = __uint_as_float(w.w & 0xffff0000u) - lse;
            p4[i * 2] = a;
            p4[i * 2 + 1] = b4;
        }
    } else {
        float4* p4 = (float4*)po;
        for (int i = tid; i < 8000; i += 256) {
            float4 v = p4[i];
            v.x -= lse; v.y -= lse; v.z -= lse; v.w -= lse;
            p4[i] = v;
        }
    }
}

// ==================================================================== launch
extern "C" void kernel_launch(void* const* d_in, const int* in_sizes, int n_in,
                              void* d_out, int out_size, void* d_ws, size_t ws_size,
                              hipStream_t stream)
{
    const int*   src     = (const int*)d_in[0];
    const int*   trg     = (const int*)d_in[2];
    const float* emb_enc = (const float*)d_in[3];
    const float* emb_dec = (const float*)d_in[4];
    const float* Wih_f   = (const float*)d_in[5];
    const float* Whh_f   = (const float*)d_in[6];
    const float* bih_f   = (const float*)d_in[7];
    const float* bhh_f   = (const float*)d_in[8];
    const float* Wih_b   = (const float*)d_in[9];
    const float* Whh_b   = (const float*)d_in[10];
    const float* bih_b   = (const float*)d_in[11];
    const float* bhh_b   = (const float*)d_in[12];
    const float* W_fc    = (const float*)d_in[13];
    const float* b_fc    = (const float*)d_in[14];
    const float* W_attn  = (const float*)d_in[15];
    const float* b_attn  = (const float*)d_in[16];
    const float* v_attn  = (const float*)d_in[17];
    const float* Wih_d   = (const float*)d_in[18];
    const float* Whh_d   = (const float*)d_in[19];
    const float* bih_d   = (const float*)d_in[20];
    const float* bhh_d   = (const float*)d_in[21];
    const float* W_out   = (const float*)d_in[22];
    const float* b_out   = (const float*)d_in[23];
    float* out = (float*)d_out;

    char* wsb = (char*)d_ws;
    size_t off = 0;
    auto alloc = [&](size_t bytes) { void* q = wsb + off; off = (off + bytes + 255) & ~(size_t)255; return q; };
    bfu*   emb_b   = (bfu*)alloc((size_t)8192 * 256 * 2);
    bfu*   encbt_b = (bfu*)alloc((size_t)8192 * 1024 * 2);
    float* encp    = (float*)alloc((size_t)8192 * 512 * 4);
    bfu*   encp_b  = (bfu*)alloc((size_t)8192 * 512 * 2);
    float* gi_f    = (float*)alloc((size_t)8192 * 1536 * 4);
    float* gi_b    = (float*)alloc((size_t)8192 * 1536 * 4);
    float* gie     = (float*)alloc((size_t)3968 * 1536 * 4);
    bfu*   wbuf    = (bfu*)alloc((size_t)128 * 1024 * 2);
    float* hA      = (float*)alloc((size_t)128 * 1024 * 4);
    float* hB      = (float*)alloc((size_t)128 * 1024 * 4);
    bfu*   hbA     = (bfu*)alloc((size_t)128 * 1024 * 2);
    bfu*   hbB     = (bfu*)alloc((size_t)128 * 1024 * 2);
    float* hdA     = (float*)alloc((size_t)128 * 512 * 4);
    float* hdB     = (float*)alloc((size_t)128 * 512 * 4);
    bfu*   hdbA    = (bfu*)alloc((size_t)128 * 512 * 2);
    bfu*   hdbB    = (bfu*)alloc((size_t)128 * 512 * 2);
    bfu*   Xb      = (bfu*)alloc((size_t)MPAD * XDIM * 2);
    bfu*   Wihf_b  = (bfu*)alloc((size_t)1536 * 256 * 2);
    bfu*   Wihb_b  = (bfu*)alloc((size_t)1536 * 256 * 2);
    bfu*   Whhf_b  = (bfu*)alloc((size_t)1536 * 512 * 2);
    bfu*   Whhb_b  = (bfu*)alloc((size_t)1536 * 512 * 2);
    bfu*   Wfc_b   = (bfu*)alloc((size_t)512 * 1024 * 2);
    bfu*   Wattn_b = (bfu*)alloc((size_t)512 * 1536 * 2);
    bfu*   WahT    = (bfu*)alloc((size_t)512 * 512 * 2);
    bfu*   Wihd_b  = (bfu*)alloc((size_t)1536 * 1280 * 2);
    bfu*   Whhd_b  = (bfu*)alloc((size_t)1536 * 512 * 2);
    bfu*   Wout_b  = (bfu*)alloc((size_t)VOCAB * XDIM * 2);

    const size_t lb_bytes = (size_t)MPAD * VOCAB * 2;
    bfu* Lb = nullptr;
    if (ws_size >= off + lb_bytes + 256) Lb = (bfu*)alloc(lb_bytes);
    const int obf = (Lb != nullptr) ? 1 : 0;

    conv_all<<<(15941632 + 255) / 256, 256, 0, stream>>>(
        Wih_f, Wih_b, Whh_f, Whh_b, W_fc, W_attn, Wih_d, Whh_d, W_out,
        Wihf_b, Wihb_b, Whhf_b, Whhb_b, Wfc_b, Wattn_b, Wihd_b, Whhd_b, Wout_b);
    transpose_wah<<<1024, 256, 0, stream>>>(W_attn, WahT);

    gather_emb<<<(8192 * 256 + 255) / 256, 256, 0, stream>>>(emb_enc, src, emb_b, 8192 * 256);
    gather_trg<<<(3968 * 256 + 255) / 256, 256, 0, stream>>>(emb_dec, trg, Xb, 3968 * 256);
    zero_kernel<<<(131072 + 255) / 256, 256, 0, stream>>>(hA, 131072);
    zero_kernel<<<(65536 + 255) / 256, 256, 0, stream>>>((float*)hbA, 65536);

    // gi for all encoder steps, both dirs
    gemm_bf16<<<dim3(12, 64, 2), 256, 0, stream>>>(
        emb_b, 256, Wihf_b, 256, gi_f, 1536, bih_f, 256,
        emb_b, 256, Wihb_b, 256, gi_b, 1536, bih_b, 256, 0, nullptr);
    // gi_e for all decoder steps
    gemm_bf16<<<dim3(12, 31, 1), 256, 0, stream>>>(
        Xb + 1536, XDIM, Wihd_b, 1280, gie, 1536, bih_d, 256,
        Xb + 1536, XDIM, Wihd_b, 1280, gie, 1536, bih_d, 256, 0, nullptr);

    // encoder: 64 fused steps (batch-split grid)
    for (int s = 0; s < S_LEN; ++s) {
        const float* hin  = (s & 1) ? hB : hA;
        float*       hout = (s & 1) ? hA : hB;
        const bfu*   hbin = (s & 1) ? hbB : hbA;
        bfu*         hbout = (s & 1) ? hbA : hbB;
        enc_step<<<dim3(32, 2, 2), 256, 0, stream>>>(
            gi_f, gi_b, Whhf_b, Whhb_b, bhh_f, bhh_b,
            hin, hout, hbin, hbout, encbt_b, s);
    }
    // hid = tanh([hf,hb] @ W_fc^T + b_fc)
    gemm_bf16<<<dim3(4, 1, 1), 256, 0, stream>>>(
        hbA, 1024, Wfc_b, 1024, hdA, 512, b_fc, 1024,
        hbA, 1024, Wfc_b, 1024, hdA, 512, b_fc, 1024, 1, hdbA);
    // enc_proj (f32 + bf16 mirror)
    gemm_bf16<<<dim3(4, 64, 1), 256, 0, stream>>>(
        encbt_b, 1024, Wattn_b + 512, 1536, encp, 512, b_attn, 1024,
        encbt_b, 1024, Wattn_b + 512, 1536, encp, 512, b_attn, 1024, 0, encp_b);

    // decoder: 31 steps x 2 launches
    for (int t = 0; t < T_LEN - 1; ++t) {
        const float* hin  = (t & 1) ? hdB : hdA;
        float*       hout = (t & 1) ? hdA : hdB;
        const bfu*   hbin = (t & 1) ? hdbB : hdbA;
        bfu*         hbout = (t & 1) ? hdbA : hdbB;
        attn_fused<<<BATCH, 256, 0, stream>>>(hbin, WahT, encp_b, encbt_b,
                                              v_attn, src, wbuf, Xb, t);
        dec_step<<<dim3(32, 2), 256, 0, stream>>>(
            gie, Whhd_b, Wihd_b, bhh_d, hbin, wbuf, hin, hout, hbout, Xb, t);
    }

    // logits (bf16 if room) + log-softmax + fill plane
    gemm_big<<<dim3(2000, 1), 512, 0, stream>>>(Xb, Wout_b, out, b_out, Lb, obf);
    log_softmax_fill<<<4096, 256, 0, stream>>>(Lb, out, obf);
}